// Round 1
// 660.778 us; speedup vs baseline: 1.1250x; 1.1250x over previous
//
#include <hip/hip_runtime.h>
#include <hip/hip_bf16.h>
#include <math.h>

#define N_NODES 100000
#define N_EDGESC 100000
#define NNZ_C   3200000
#define D_IN    512
#define D_HID   16
#define N_CLS   7
#define NBK     782   // ceil(100000/128) node buckets, bucket = v>>7

// k1 block-range split
#define G_GEMM 1563   // ceil(6250/4) : gemm1, 4 waves/block, 16 rows/wave
#define G_EOFF 12500  // ceil(NNZ/256)
#define G_HIST 250    // 250 * 12800 = NNZ
// k3 block-range split
#define G_BIN  250

typedef short short8 __attribute__((ext_vector_type(8)));
typedef float f32x4  __attribute__((ext_vector_type(4)));

__device__ __forceinline__ unsigned short f2bf_rn(float x) {
  unsigned int u = __float_as_uint(x);
  u += 0x7fff + ((u >> 16) & 1);
  return (unsigned short)(u >> 16);
}
__device__ __forceinline__ float bf2f(unsigned short b) {
  return __uint_as_float(((unsigned int)b) << 16);
}

// ---------------- setup bodies ----------------
__device__ __forceinline__ void eoff_body(int b, const int* __restrict__ eidx,
                                          int* __restrict__ eoff) {
  int i = b * 256 + threadIdx.x;
  if (i >= NNZ_C) return;
  int ec = eidx[i];
  int ep = (i == 0) ? -1 : eidx[i - 1];
  for (int e = ep + 1; e <= ec; ++e) eoff[e] = i;
  if (i == NNZ_C - 1) {
    for (int e = ec + 1; e <= N_EDGESC; ++e) eoff[e] = NNZ_C;
  }
}

__device__ __forceinline__ void hist_body(int b, const int* __restrict__ nidx,
                                          int* __restrict__ gcnt) {
  __shared__ int lh[NBK];
  int t = threadIdx.x;
  for (int i = t; i < NBK; i += 256) lh[i] = 0;
  __syncthreads();
  int base = b * 12800;
  for (int it = 0; it < 50; ++it) {
    int i = base + it * 256 + t;
    if (i < NNZ_C) atomicAdd(&lh[nidx[i] >> 7], 1);
  }
  __syncthreads();
  for (int i = t; i < NBK; i += 256) {
    int c = lh[i];
    if (c) atomicAdd(&gcnt[i], c);
  }
}

__device__ __forceinline__ void bin_body(int b, const int* __restrict__ nidx,
                                         const int* __restrict__ eidx,
                                         int* __restrict__ bcur, int* __restrict__ binned) {
  __shared__ int lh[NBK];
  __shared__ int gb[NBK];
  int t = threadIdx.x;
  for (int i = t; i < NBK; i += 256) lh[i] = 0;
  __syncthreads();
  int base = b * 12800;
  for (int it = 0; it < 50; ++it) {
    int i = base + it * 256 + t;
    if (i < NNZ_C) atomicAdd(&lh[nidx[i] >> 7], 1);
  }
  __syncthreads();
  for (int i = t; i < NBK; i += 256) {
    int c = lh[i];
    gb[i] = c ? atomicAdd(&bcur[i], c) : 0;
    lh[i] = 0;
  }
  __syncthreads();
  for (int it = 0; it < 50; ++it) {
    int i = base + it * 256 + t;
    if (i < NNZ_C) {
      int v = nidx[i], e = eidx[i];
      int bk = v >> 7;
      int r = atomicAdd(&lh[bk], 1);
      binned[gb[bk] + r] = e | ((v & 127) << 20);
    }
  }
}

// ---------------- setup: scan bucket counts -> boff, init bcur ----------------
__global__ void bscan_kernel(const int* __restrict__ gcnt, int* __restrict__ boff,
                             int* __restrict__ bcur) {
  __shared__ int lds[1024];
  int t = threadIdx.x;
  int v = (t < NBK) ? gcnt[t] : 0;
  lds[t] = v;
  __syncthreads();
  for (int d = 1; d < 1024; d <<= 1) {
    int u = (t >= d) ? lds[t - d] : 0;
    __syncthreads();
    lds[t] += u;
    __syncthreads();
  }
  if (t < NBK) {
    boff[t + 1] = lds[t];
    bcur[t] = lds[t] - v;   // exclusive
  }
  if (t == 0) boff[0] = 0;
}

// ---------------- setup: per-bucket node-CSR (noff + perm_e) ----------------
__global__ void csr_kernel(const int* __restrict__ binned, const int* __restrict__ boff,
                           int* __restrict__ noff, int* __restrict__ perm_e, int N) {
  __shared__ int lh[128];
  __shared__ int lsc[128];
  __shared__ int lcur[128];
  int b = blockIdx.x;
  int t = threadIdx.x;
  int s = boff[b], e = boff[b + 1];
  if (t < 128) lh[t] = 0;
  __syncthreads();
  for (int i = s + t; i < e; i += 256) {
    atomicAdd(&lh[binned[i] >> 20], 1);
  }
  __syncthreads();
  if (t < 128) lsc[t] = lh[t];
  __syncthreads();
  for (int d = 1; d < 128; d <<= 1) {
    int u = (t < 128 && t >= d) ? lsc[t - d] : 0;
    __syncthreads();
    if (t < 128) lsc[t] += u;
    __syncthreads();
  }
  if (t < 128) {
    int excl = lsc[t] - lh[t];
    lcur[t] = excl;
    int n = b * 128 + t;
    if (n <= N) noff[n] = s + excl;
  }
  __syncthreads();
  for (int i = s + t; i < e; i += 256) {
    int p = binned[i];
    int r = atomicAdd(&lcur[p >> 20], 1);
    perm_e[s + r] = p & 0xFFFFF;
  }
}

// ---------------- GEMM1 body via MFMA (bf16 3-term split) ----------------
__device__ __forceinline__ void gemm1_body(int b,
    const float* __restrict__ X, const float* __restrict__ W,
    const float* __restrict__ a1, const float* __restrict__ a2,
    float* __restrict__ Hout, float2* __restrict__ phv) {
  int wid = b * 4 + (threadIdx.x >> 6);
  if (wid >= 6250) return;
  int lane = threadIdx.x & 63;
  int col  = lane & 15;
  int quad = lane >> 4;

  short8 wh[16], wl[16];
#pragma unroll
  for (int c = 0; c < 16; ++c) {
#pragma unroll
    for (int j = 0; j < 8; ++j) {
      float w = W[(c * 32 + quad * 8 + j) * 16 + col];
      unsigned short h = f2bf_rn(w);
      wh[c][j] = (short)h;
      wl[c][j] = (short)f2bf_rn(w - bf2f(h));
    }
  }

  int rowbase = wid * 16;
  const float4* Xr = (const float4*)(X + (size_t)(rowbase + col) * D_IN) + quad * 2;

  f32x4 acc_hh = {0.f, 0.f, 0.f, 0.f};
  f32x4 acc_hl = {0.f, 0.f, 0.f, 0.f};
  f32x4 acc_lh = {0.f, 0.f, 0.f, 0.f};

  float4 u0 = Xr[0], u1 = Xr[1];
#pragma unroll
  for (int c = 0; c < 16; ++c) {
    float4 n0, n1;
    if (c < 15) { n0 = Xr[(c + 1) * 8]; n1 = Xr[(c + 1) * 8 + 1]; }
    float xs[8] = {u0.x, u0.y, u0.z, u0.w, u1.x, u1.y, u1.z, u1.w};
    short8 ah, al;
#pragma unroll
    for (int j = 0; j < 8; ++j) {
      unsigned short h = f2bf_rn(xs[j]);
      ah[j] = (short)h;
      al[j] = (short)f2bf_rn(xs[j] - bf2f(h));
    }
    acc_hh = __builtin_amdgcn_mfma_f32_16x16x32_bf16(ah, wh[c], acc_hh, 0, 0, 0);
    acc_hl = __builtin_amdgcn_mfma_f32_16x16x32_bf16(ah, wl[c], acc_hl, 0, 0, 0);
    acc_lh = __builtin_amdgcn_mfma_f32_16x16x32_bf16(al, wh[c], acc_lh, 0, 0, 0);
    u0 = n0; u1 = n1;
  }

  float a1c = a1[col], a2c = a2[col];
#pragma unroll
  for (int r = 0; r < 4; ++r) {
    float v = acc_hh[r] + acc_hl[r] + acc_lh[r];
    int row = rowbase + quad * 4 + r;
    Hout[(size_t)row * 16 + col] = v;
    float p1 = v * a1c, p2 = v * a2c;
#pragma unroll
    for (int d = 1; d < 16; d <<= 1) { p1 += __shfl_xor(p1, d); p2 += __shfl_xor(p2, d); }
    if (col == 0) phv[row] = make_float2(p1, p2);
  }
}

// ---------------- K1: gemm1 || eoff || hist (independent work, one dispatch) ------
__global__ __launch_bounds__(256) void k1_kernel(
    const float* __restrict__ X, const float* __restrict__ W1,
    const float* __restrict__ a1, const float* __restrict__ a2,
    float* __restrict__ Hout, float2* __restrict__ phv,
    const int* __restrict__ eidx, int* __restrict__ eoff,
    const int* __restrict__ nidx, int* __restrict__ gcnt) {
  int b = blockIdx.x;
  if (b < G_GEMM) {
    gemm1_body(b, X, W1, a1, a2, Hout, phv);
  } else if (b < G_GEMM + G_EOFF) {
    eoff_body(b - G_GEMM, eidx, eoff);
  } else {
    hist_body(b - G_GEMM - G_EOFF, nidx, gcnt);
  }
}

// ---------------- edge phase: single-pass online softmax, unroll-2 ----------------
template <int D, int GROUP>
__device__ __forceinline__ void edge_body(
    const float* __restrict__ h, const float2* __restrict__ phv,
    const float* __restrict__ a2, const int* __restrict__ eoff,
    const int* __restrict__ nidx, float* __restrict__ eout,
    float* __restrict__ pe, int E, int wave, int lane) {
  constexpr int NG = 64 / GROUP;
  if (wave >= E) return;
  int o0 = eoff[wave], o1 = eoff[wave + 1];
  int g = lane / GROUP, t = lane % GROUP;
  if (o0 == o1) {
    if (g == 0) {
      if (t < D) eout[(size_t)wave * D + t] = 0.f;
      if (t == 0) pe[wave] = 0.f;
    }
    return;
  }
  float m = -1e30f, l = 0.f, acc = 0.f;
  for (int i = o0 + g; i < o1; i += 2 * NG) {
    int i2 = i + NG;
    bool okb = i2 < o1;
    int va = nidx[i];
    int vb = okb ? nidx[i2] : va;
    float pa_ = phv[va].x;
    float pb_ = phv[vb].x;
    float ha = (t < D) ? h[(size_t)va * D + t] : 0.f;
    float hb = (t < D) ? h[(size_t)vb * D + t] : 0.f;
    float sa = pa_ > 0.f ? pa_ : 0.2f * pa_;
    float sb = pb_ > 0.f ? pb_ : 0.2f * pb_;
    if (!okb) sb = -1e30f;               // predicated tail: exp -> 0
    float mn = fmaxf(m, fmaxf(sa, sb));
    float eo = __expf(m - mn);           // 1 when m unchanged, 0 on first iter
    float exa = __expf(sa - mn);
    float exb = __expf(sb - mn);
    l = l * eo + exa + exb;
    acc = acc * eo + exa * ha + exb * hb;
    m = mn;
  }
  // cross-group merge (log2(NG) steps)
#pragma unroll
  for (int d = GROUP; d < 64; d <<= 1) {
    float mo = __shfl_xor(m, d), lo = __shfl_xor(l, d), ao = __shfl_xor(acc, d);
    float mn = fmaxf(m, mo);
    float e0 = __expf(m - mn), e1x = __expf(mo - mn);
    l = l * e0 + lo * e1x;
    acc = acc * e0 + ao * e1x;
    m = mn;
  }
  float val = acc / (l + 1e-9f);
  float pav = (t < D) ? val * a2[D + t] : 0.f;
#pragma unroll
  for (int d = 1; d < GROUP; d <<= 1) pav += __shfl_xor(pav, d);
  if (g == 0) {
    if (t < D) eout[(size_t)wave * D + t] = val;
    if (t == 0) pe[wave] = pav;
  }
}

template <int D, int GROUP>
__global__ void edge_kernel(const float* __restrict__ h, const float2* __restrict__ phv,
                            const float* __restrict__ a2, const int* __restrict__ eoff,
                            const int* __restrict__ nidx, float* __restrict__ eout,
                            float* __restrict__ pe, int E) {
  int wave = (blockIdx.x * blockDim.x + threadIdx.x) >> 6;
  edge_body<D, GROUP>(h, phv, a2, eoff, nidx, eout, pe, E, wave, threadIdx.x & 63);
}

// ---------------- K3: bin || edge1 (independent, one dispatch) ----------------
__global__ void k3_kernel(const int* __restrict__ nidx, const int* __restrict__ eidx,
                          int* __restrict__ bcur, int* __restrict__ binned,
                          const float* __restrict__ h1g, const float2* __restrict__ phv,
                          const float* __restrict__ a2_1, const int* __restrict__ eoff,
                          float* __restrict__ e1, float* __restrict__ pe) {
  int b = blockIdx.x;
  if (b < G_BIN) {
    bin_body(b, nidx, eidx, bcur, binned);
  } else {
    int wave = (b - G_BIN) * 4 + (threadIdx.x >> 6);
    edge_body<D_HID, 16>(h1g, phv, a2_1, eoff, nidx, e1, pe, N_EDGESC,
                         wave, threadIdx.x & 63);
  }
}

// ---------------- node phase 1 (D=16), fused gemm2 + phv epilogue ----------------
__global__ void node1_kernel(float2* phv, const float* __restrict__ e1,
                             const float* __restrict__ pe, const int* __restrict__ noff,
                             const int* __restrict__ perm_e, float* __restrict__ H1out,
                             float* __restrict__ h2g, const float* __restrict__ W2,
                             const float* __restrict__ a1_2, const float* __restrict__ a2_2,
                             int N) {
  int wave = (blockIdx.x * blockDim.x + threadIdx.x) >> 6;
  int lane = threadIdx.x & 63;
  if (wave >= N) return;
  int o0 = noff[wave], o1 = noff[wave + 1];
  int g = lane >> 4, t = lane & 15;
  float ph = phv[wave].y;
  float m = -1e30f, l = 0.f, acc = 0.f;
  for (int i = o0 + g; i < o1; i += 8) {
    int i2 = i + 4;
    bool okb = i2 < o1;
    int ea = perm_e[i];
    int eb = okb ? perm_e[i2] : ea;
    float pa_ = ph + pe[ea];
    float pb_ = ph + pe[eb];
    float va = e1[(size_t)ea * 16 + t];
    float vb = e1[(size_t)eb * 16 + t];
    float sa = pa_ > 0.f ? pa_ : 0.2f * pa_;
    float sb = pb_ > 0.f ? pb_ : 0.2f * pb_;
    if (!okb) sb = -1e30f;
    float mn = fmaxf(m, fmaxf(sa, sb));
    float eo = __expf(m - mn);
    float exa = __expf(sa - mn);
    float exb = __expf(sb - mn);
    l = l * eo + exa + exb;
    acc = acc * eo + exa * va + exb * vb;
    m = mn;
  }
#pragma unroll
  for (int d = 16; d < 64; d <<= 1) {
    float mo = __shfl_xor(m, d), lo = __shfl_xor(l, d), ao = __shfl_xor(acc, d);
    float mn = fmaxf(m, mo);
    float e0 = __expf(m - mn), e1x = __expf(mo - mn);
    l = l * e0 + lo * e1x;
    acc = acc * e0 + ao * e1x;
    m = mn;
  }
  float val = acc / (l + 1e-9f);            // H1[wave][t]  (empty -> 0, matches ref)
  if (g == 0) H1out[(size_t)wave * 16 + t] = val;
  // fused gemm2: h2 = elu(H1) @ W2, plus phv epilogue for layer 2
  float x = val > 0.f ? val : expm1f(val);
  float p1 = 0.f, p2 = 0.f, myh2 = 0.f;
#pragma unroll
  for (int j = 0; j < N_CLS; ++j) {
    float term = x * W2[t * N_CLS + j];
#pragma unroll
    for (int d = 1; d < 16; d <<= 1) term += __shfl_xor(term, d);
    p1 += term * a1_2[j];
    p2 += term * a2_2[j];
    if (t == j) myh2 = term;
  }
  if (g == 0) {
    if (t < N_CLS) h2g[(size_t)wave * N_CLS + t] = myh2;
    if (t == 0) phv[wave] = make_float2(p1, p2);
  }
}

// ---------------- node phase 2 (D=7), fused log_softmax ----------------
__global__ void node2_kernel(const float2* __restrict__ phv, const float* __restrict__ e2,
                             const float* __restrict__ pe, const int* __restrict__ noff,
                             const int* __restrict__ perm_e, float* __restrict__ H2out,
                             float* __restrict__ logp, int N) {
  int wave = (blockIdx.x * blockDim.x + threadIdx.x) >> 6;
  int lane = threadIdx.x & 63;
  if (wave >= N) return;
  int o0 = noff[wave], o1 = noff[wave + 1];
  int g = lane >> 3, t = lane & 7;
  float ph = phv[wave].y;
  float m = -1e30f, l = 0.f, acc = 0.f;
  for (int i = o0 + g; i < o1; i += 16) {
    int i2 = i + 8;
    bool okb = i2 < o1;
    int ea = perm_e[i];
    int eb = okb ? perm_e[i2] : ea;
    float pa_ = ph + pe[ea];
    float pb_ = ph + pe[eb];
    float va = (t < N_CLS) ? e2[(size_t)ea * N_CLS + t] : 0.f;
    float vb = (t < N_CLS) ? e2[(size_t)eb * N_CLS + t] : 0.f;
    float sa = pa_ > 0.f ? pa_ : 0.2f * pa_;
    float sb = pb_ > 0.f ? pb_ : 0.2f * pb_;
    if (!okb) sb = -1e30f;
    float mn = fmaxf(m, fmaxf(sa, sb));
    float eo = __expf(m - mn);
    float exa = __expf(sa - mn);
    float exb = __expf(sb - mn);
    l = l * eo + exa + exb;
    acc = acc * eo + exa * va + exb * vb;
    m = mn;
  }
#pragma unroll
  for (int d = 8; d < 64; d <<= 1) {
    float mo = __shfl_xor(m, d), lo = __shfl_xor(l, d), ao = __shfl_xor(acc, d);
    float mn = fmaxf(m, mo);
    float e0 = __expf(m - mn), e1x = __expf(mo - mn);
    l = l * e0 + lo * e1x;
    acc = acc * e0 + ao * e1x;
    m = mn;
  }
  float val = acc / (l + 1e-9f);            // H2[wave][t]  (empty -> 0)
  if (g == 0 && t < N_CLS) H2out[(size_t)wave * N_CLS + t] = val;
  // fused log_softmax over the 7 classes (within each 8-lane group)
  float xm = (t < N_CLS) ? val : -1e30f;
#pragma unroll
  for (int d = 1; d < 8; d <<= 1) xm = fmaxf(xm, __shfl_xor(xm, d));
  float se = (t < N_CLS) ? __expf(val - xm) : 0.f;
#pragma unroll
  for (int d = 1; d < 8; d <<= 1) se += __shfl_xor(se, d);
  float lg = logf(se);
  if (g == 0 && t < N_CLS) logp[(size_t)wave * N_CLS + t] = val - xm - lg;
}

// ---------------- launch ----------------
extern "C" void kernel_launch(void* const* d_in, const int* in_sizes, int n_in,
                              void* d_out, int out_size, void* d_ws, size_t ws_size,
                              hipStream_t stream) {
  const float* H    = (const float*)d_in[0];
  const float* W1   = (const float*)d_in[1];
  const float* a1_1 = (const float*)d_in[2];
  const float* a2_1 = (const float*)d_in[3];
  const float* W2   = (const float*)d_in[4];
  const float* a1_2 = (const float*)d_in[5];
  const float* a2_2 = (const float*)d_in[6];
  const int* nidx   = (const int*)d_in[7];
  const int* eidx   = (const int*)d_in[8];

  float* outp = (float*)d_out;
  float* logp = outp;                                   // [N,7]
  float* H1   = outp + (size_t)N_NODES * N_CLS;         // [N,16]
  float* H2   = H1 + (size_t)N_NODES * D_HID;           // [N,7]

  char* ws = (char*)d_ws;
  float* h1g  = (float*)(ws + 0);          //  6,400,000 B : N x 16
  float* e1   = (float*)(ws + 6400000);    //  6,400,000 B : E x 16
  float* h2g  = (float*)(ws + 12800000);   //  2,800,000 B : N x 7
  float* e2   = (float*)(ws + 15600000);   //  2,800,000 B : E x 7
  int* eoff   = (int*)(ws + 18400000);     //    400,004 B : E+1
  int* noff   = (int*)(ws + 18800128);     //    400,004 B : N+1
  float* pe   = (float*)(ws + 19200256);   //    400,000 B : E
  int* perm_e = (int*)(ws + 19600384);     // 12,800,000 B : NNZ
  float2* phv = (float2*)(ws + 32400384);  //    800,000 B : N x {p_a1, p_a2}
  int* gcnt   = (int*)(ws + 33200384);     //      3,128 B : NBK
  int* boff   = (int*)(ws + 33203584);     //      3,132 B : NBK+1
  int* bcur   = (int*)(ws + 33206784);     //      3,128 B : NBK
  int* binned = (int*)(ws + 33210368);     // 12,800,000 B : NNZ (no longer aliased:
                                           //   gemm1 now runs before bin writes it)

  const int TB = 256;

  hipMemsetAsync(gcnt, 0, NBK * sizeof(int), stream);
  // K1: gemm1 (X read, BW-bound) overlapped with eoff + hist streaming
  k1_kernel<<<G_GEMM + G_EOFF + G_HIST, TB, 0, stream>>>(
      H, W1, a1_1, a2_1, h1g, phv, eidx, eoff, nidx, gcnt);
  bscan_kernel<<<1, 1024, 0, stream>>>(gcnt, boff, bcur);
  // K3: bin (needs bscan) overlapped with edge phase 1 (needs only K1 outputs)
  k3_kernel<<<G_BIN + 25000, TB, 0, stream>>>(
      nidx, eidx, bcur, binned, h1g, phv, a2_1, eoff, e1, pe);
  csr_kernel<<<NBK, TB, 0, stream>>>(binned, boff, noff, perm_e, N_NODES);
  // node phase 1 + fused gemm2 + layer-2 phv
  node1_kernel<<<25000, TB, 0, stream>>>(phv, e1, pe, noff, perm_e, H1, h2g,
                                         W2, a1_2, a2_2, N_NODES);
  // layer 2
  edge_kernel<N_CLS, 8><<<25000, TB, 0, stream>>>(h2g, phv, a2_2, eoff, nidx, e2, pe, N_EDGESC);
  node2_kernel<<<25000, TB, 0, stream>>>(phv, e2, pe, noff, perm_e, H2, logp, N_NODES);
}

// Round 4
// 627.051 us; speedup vs baseline: 1.1855x; 1.0538x over previous
//
#include <hip/hip_runtime.h>
#include <hip/hip_bf16.h>
#include <math.h>

#define N_NODES 100000
#define N_EDGESC 100000
#define NNZ_C   3200000
#define D_IN    512
#define D_HID   16
#define N_CLS   7
#define NBK     782   // ceil(100000/128) node buckets, bucket = v>>7

// k1 block-range split
#define G_GEMM 1563   // ceil(6250/4) : gemm1, 4 waves/block, 16 rows/wave
#define G_HIST 1000   // 3200 entries each
#define G_EOFF 3125   // 1024 entries each (4 per thread)
// k3 block-range split
#define G_BIN  1000   // 3200 entries each

typedef short short8 __attribute__((ext_vector_type(8)));
typedef float f32x4  __attribute__((ext_vector_type(4)));

__device__ __forceinline__ unsigned short f2bf_rn(float x) {
  unsigned int u = __float_as_uint(x);
  u += 0x7fff + ((u >> 16) & 1);
  return (unsigned short)(u >> 16);
}
__device__ __forceinline__ float bf2f(unsigned short b) {
  return __uint_as_float(((unsigned int)b) << 16);
}

// ---------------- setup bodies ----------------
__device__ __forceinline__ void eoff_body(int b, const int* __restrict__ eidx,
                                          int* __restrict__ eoff) {
  int i0 = (b * 256 + threadIdx.x) * 4;
  if (i0 >= NNZ_C) return;
  int4 v4 = *(const int4*)(eidx + i0);
  int vv[4] = {v4.x, v4.y, v4.z, v4.w};
  int prev = (i0 == 0) ? -1 : eidx[i0 - 1];
#pragma unroll
  for (int k = 0; k < 4; ++k) {
    for (int e = prev + 1; e <= vv[k]; ++e) eoff[e] = i0 + k;
    prev = vv[k];
  }
  if (i0 + 4 == NNZ_C) {
    for (int e = prev + 1; e <= N_EDGESC; ++e) eoff[e] = NNZ_C;
  }
}

__device__ __forceinline__ void hist_body(int b, const int* __restrict__ nidx,
                                          int* __restrict__ gcnt) {
  __shared__ int lh[NBK];
  int t = threadIdx.x;
  for (int i = t; i < NBK; i += 256) lh[i] = 0;
  __syncthreads();
  int base = b * 3200, end = base + 3200;
  for (int i = base + t; i < end; i += 256) atomicAdd(&lh[nidx[i] >> 7], 1);
  __syncthreads();
  for (int i = t; i < NBK; i += 256) {
    int c = lh[i];
    if (c) atomicAdd(&gcnt[i], c);
  }
}

__device__ __forceinline__ void bin_body(int b, const int* __restrict__ nidx,
                                         const int* __restrict__ eidx,
                                         int* __restrict__ bcur, int* __restrict__ binned) {
  __shared__ int lh[NBK];
  __shared__ int gb[NBK];
  int t = threadIdx.x;
  for (int i = t; i < NBK; i += 256) lh[i] = 0;
  __syncthreads();
  int base = b * 3200, end = base + 3200;
  for (int i = base + t; i < end; i += 256) atomicAdd(&lh[nidx[i] >> 7], 1);
  __syncthreads();
  for (int i = t; i < NBK; i += 256) {
    int c = lh[i];
    gb[i] = c ? atomicAdd(&bcur[i], c) : 0;
    lh[i] = 0;
  }
  __syncthreads();
  for (int i = base + t; i < end; i += 256) {
    int v = nidx[i], e = eidx[i];
    int bk = v >> 7;
    int r = atomicAdd(&lh[bk], 1);
    binned[gb[bk] + r] = e | ((v & 127) << 20);
  }
}

// ---------------- setup: scan bucket counts -> boff, init bcur ----------------
__global__ void bscan_kernel(const int* __restrict__ gcnt, int* __restrict__ boff,
                             int* __restrict__ bcur) {
  __shared__ int lds[1024];
  int t = threadIdx.x;
  int v = (t < NBK) ? gcnt[t] : 0;
  lds[t] = v;
  __syncthreads();
  for (int d = 1; d < 1024; d <<= 1) {
    int u = (t >= d) ? lds[t - d] : 0;
    __syncthreads();
    lds[t] += u;
    __syncthreads();
  }
  if (t < NBK) {
    boff[t + 1] = lds[t];
    bcur[t] = lds[t] - v;   // exclusive
  }
  if (t == 0) boff[0] = 0;
}

// ---------------- setup: per-bucket node-CSR (noff + perm_e) ----------------
__global__ void csr_kernel(const int* __restrict__ binned, const int* __restrict__ boff,
                           int* __restrict__ noff, int* __restrict__ perm_e, int N) {
  __shared__ int lh[128];
  __shared__ int lsc[128];
  __shared__ int lcur[128];
  int b = blockIdx.x;
  int t = threadIdx.x;
  int s = boff[b], e = boff[b + 1];
  if (t < 128) lh[t] = 0;
  __syncthreads();
  for (int i = s + t; i < e; i += 256) {
    atomicAdd(&lh[binned[i] >> 20], 1);
  }
  __syncthreads();
  if (t < 128) lsc[t] = lh[t];
  __syncthreads();
  for (int d = 1; d < 128; d <<= 1) {
    int u = (t < 128 && t >= d) ? lsc[t - d] : 0;
    __syncthreads();
    if (t < 128) lsc[t] += u;
    __syncthreads();
  }
  if (t < 128) {
    int excl = lsc[t] - lh[t];
    lcur[t] = excl;
    int n = b * 128 + t;
    if (n <= N) noff[n] = s + excl;
  }
  __syncthreads();
  for (int i = s + t; i < e; i += 256) {
    int p = binned[i];
    int r = atomicAdd(&lcur[p >> 20], 1);
    perm_e[s + r] = p & 0xFFFFF;
  }
}

// ---------------- GEMM1 body via MFMA (bf16 3-term split), distance-2 prefetch ----
__device__ __forceinline__ void gemm1_body(int b,
    const float* __restrict__ X, const float* __restrict__ W,
    const float* __restrict__ a1, const float* __restrict__ a2,
    float* __restrict__ Hout, float2* __restrict__ phv) {
  int wid = b * 4 + (threadIdx.x >> 6);
  if (wid >= 6250) return;
  int lane = threadIdx.x & 63;
  int col  = lane & 15;
  int quad = lane >> 4;

  short8 wh[16], wl[16];
#pragma unroll
  for (int c = 0; c < 16; ++c) {
#pragma unroll
    for (int j = 0; j < 8; ++j) {
      float w = W[(c * 32 + quad * 8 + j) * 16 + col];
      unsigned short h = f2bf_rn(w);
      wh[c][j] = (short)h;
      wl[c][j] = (short)f2bf_rn(w - bf2f(h));
    }
  }

  int rowbase = wid * 16;
  const float4* Xr = (const float4*)(X + (size_t)(rowbase + col) * D_IN) + quad * 2;

  f32x4 acc_hh = {0.f, 0.f, 0.f, 0.f};
  f32x4 acc_hl = {0.f, 0.f, 0.f, 0.f};
  f32x4 acc_lh = {0.f, 0.f, 0.f, 0.f};

  float4 A0 = Xr[0], A1 = Xr[1];
  float4 B0 = Xr[8], B1 = Xr[9];
#pragma unroll
  for (int c = 0; c < 16; ++c) {
    float4 C0 = B0, C1 = B1;
    if (c < 14) { C0 = Xr[(c + 2) * 8]; C1 = Xr[(c + 2) * 8 + 1]; }
    float xs[8] = {A0.x, A0.y, A0.z, A0.w, A1.x, A1.y, A1.z, A1.w};
    short8 ah, al;
#pragma unroll
    for (int j = 0; j < 8; ++j) {
      unsigned short h = f2bf_rn(xs[j]);
      ah[j] = (short)h;
      al[j] = (short)f2bf_rn(xs[j] - bf2f(h));
    }
    acc_hh = __builtin_amdgcn_mfma_f32_16x16x32_bf16(ah, wh[c], acc_hh, 0, 0, 0);
    acc_hl = __builtin_amdgcn_mfma_f32_16x16x32_bf16(ah, wl[c], acc_hl, 0, 0, 0);
    acc_lh = __builtin_amdgcn_mfma_f32_16x16x32_bf16(al, wh[c], acc_lh, 0, 0, 0);
    A0 = B0; A1 = B1; B0 = C0; B1 = C1;
  }

  float a1c = a1[col], a2c = a2[col];
#pragma unroll
  for (int r = 0; r < 4; ++r) {
    float v = acc_hh[r] + acc_hl[r] + acc_lh[r];
    int row = rowbase + quad * 4 + r;
    Hout[(size_t)row * 16 + col] = v;
    float p1 = v * a1c, p2 = v * a2c;
#pragma unroll
    for (int d = 1; d < 16; d <<= 1) { p1 += __shfl_xor(p1, d); p2 += __shfl_xor(p2, d); }
    if (col == 0) phv[row] = make_float2(p1, p2);
  }
}

// ---------------- K1: gemm1 || hist || eoff ----------------
__global__ __launch_bounds__(256) void k1_kernel(
    const float* __restrict__ X, const float* __restrict__ W1,
    const float* __restrict__ a1_1, const float* __restrict__ a2_1,
    float* __restrict__ Hout, float2* __restrict__ phv,
    const int* __restrict__ eidx, int* __restrict__ eoff,
    const int* __restrict__ nidx, int* __restrict__ gcnt) {
  int b = blockIdx.x;
  if (b < G_GEMM) {
    gemm1_body(b, X, W1, a1_1, a2_1, Hout, phv);
  } else if (b < G_GEMM + G_HIST) {
    hist_body(b - G_GEMM, nidx, gcnt);
  } else {
    eoff_body(b - G_GEMM - G_HIST, eidx, eoff);
  }
}

// ---------------- edge phase: round-1 numerics (phv.x scores, 2-way online SM).
// Indices tile-preloaded + shfl-distributed with a WAVE-UNIFORM inner trip count:
// every lane runs every iteration (loop bound depends only on nrem), validity is
// predicated by value (s=-1e30, weight forced to 0). All shfl sources are always
// active lanes with j, j+NG <= 63, so ds_bpermute is well-defined. For valid
// entries the arithmetic is bitwise-identical to round 1; invalid iterations are
// exact no-ops (eo=1, +0).
template <int D, int GROUP>
__device__ __forceinline__ void edge_body(
    const float* __restrict__ h, const float2* __restrict__ phv,
    const float* __restrict__ a2, const int* __restrict__ eoff,
    const int* __restrict__ nidx, float* __restrict__ eout,
    float* __restrict__ pe, int E, int wave, int lane) {
  constexpr int NG = 64 / GROUP;
  if (wave >= E) return;
  int o0 = eoff[wave], o1 = eoff[wave + 1];
  int g = lane / GROUP, t = lane % GROUP;
  if (o0 == o1) {
    if (g == 0) {
      if (t < D) eout[(size_t)wave * D + t] = 0.f;
      if (t == 0) pe[wave] = 0.f;
    }
    return;
  }
  float m = -1e30f, l = 0.f, acc = 0.f;
  for (int base = o0; base < o1; base += 64) {
    int nrem = o1 - base; if (nrem > 64) nrem = 64;
    int li = base + lane;
    int idx_l = nidx[li < o1 ? li : o1 - 1];
    for (int jb = 0; jb < nrem; jb += 2 * NG) {   // uniform bound across wave
      int j = jb + g;                              // j <= 63-NG, j+NG <= 63
      bool oka = j < nrem;
      bool okb = j + NG < nrem;
      int va = __shfl(idx_l, j);
      int vb = __shfl(idx_l, j + NG);
      float pa_ = phv[va].x;
      float pb_ = phv[vb].x;
      float ha = (t < D) ? h[(size_t)va * D + t] : 0.f;
      float hb = (t < D) ? h[(size_t)vb * D + t] : 0.f;
      float sa = oka ? (pa_ > 0.f ? pa_ : 0.2f * pa_) : -1e30f;
      float sb = okb ? (pb_ > 0.f ? pb_ : 0.2f * pb_) : -1e30f;
      float mn = fmaxf(m, fmaxf(sa, sb));
      float eo = __expf(m - mn);
      float exa = oka ? __expf(sa - mn) : 0.f;
      float exb = okb ? __expf(sb - mn) : 0.f;
      l = l * eo + exa + exb;
      acc = acc * eo + exa * ha + exb * hb;
      m = mn;
    }
  }
#pragma unroll
  for (int d = GROUP; d < 64; d <<= 1) {
    float mo = __shfl_xor(m, d), lo = __shfl_xor(l, d), ao = __shfl_xor(acc, d);
    float mn = fmaxf(m, mo);
    float e0 = __expf(m - mn), e1x = __expf(mo - mn);
    l = l * e0 + lo * e1x;
    acc = acc * e0 + ao * e1x;
    m = mn;
  }
  float val = acc / (l + 1e-9f);
  float pav = (t < D) ? val * a2[D + t] : 0.f;
#pragma unroll
  for (int d = 1; d < GROUP; d <<= 1) pav += __shfl_xor(pav, d);
  if (g == 0) {
    if (t < D) eout[(size_t)wave * D + t] = val;
    if (t == 0) pe[wave] = pav;
  }
}

template <int D, int GROUP>
__global__ __launch_bounds__(256) void edge_kernel(
    const float* __restrict__ h, const float2* __restrict__ phv,
    const float* __restrict__ a2, const int* __restrict__ eoff,
    const int* __restrict__ nidx, float* __restrict__ eout,
    float* __restrict__ pe, int E) {
  int wave = (blockIdx.x * blockDim.x + threadIdx.x) >> 6;
  edge_body<D, GROUP>(h, phv, a2, eoff, nidx, eout, pe, E, wave, threadIdx.x & 63);
}

// ---------------- K3: bin || edge1 ----------------
__global__ __launch_bounds__(256) void k3_kernel(
    const int* __restrict__ nidx, const int* __restrict__ eidx,
    int* __restrict__ bcur, int* __restrict__ binned,
    const float* __restrict__ h1g, const float2* __restrict__ phv,
    const float* __restrict__ a2_1, const int* __restrict__ eoff,
    float* __restrict__ e1, float* __restrict__ pe) {
  int b = blockIdx.x;
  if (b < G_BIN) {
    bin_body(b, nidx, eidx, bcur, binned);
  } else {
    int wave = (b - G_BIN) * 4 + (threadIdx.x >> 6);
    edge_body<D_HID, 16>(h1g, phv, a2_1, eoff, nidx, e1, pe, N_EDGESC,
                         wave, threadIdx.x & 63);
  }
}

// ---------------- node phase 1 (D=16), round-1 numerics + fused gemm2 ----------------
__global__ __launch_bounds__(256) void node1_kernel(
    float2* phv, const float* __restrict__ e1,
    const float* __restrict__ pe, const int* __restrict__ noff,
    const int* __restrict__ perm_e, float* __restrict__ H1out,
    float* __restrict__ h2g, const float* __restrict__ W2,
    const float* __restrict__ a1_2, const float* __restrict__ a2_2) {
  int wave = (blockIdx.x * blockDim.x + threadIdx.x) >> 6;
  int lane = threadIdx.x & 63;
  if (wave >= N_NODES) return;
  int o0 = noff[wave], o1 = noff[wave + 1];
  int g = lane >> 4, t = lane & 15;
  float ph = phv[wave].y;
  float m = -1e30f, l = 0.f, acc = 0.f;
  for (int base = o0; base < o1; base += 64) {
    int nrem = o1 - base; if (nrem > 64) nrem = 64;
    int li = base + lane;
    int idx_l = perm_e[li < o1 ? li : o1 - 1];
    for (int jb = 0; jb < nrem; jb += 8) {        // uniform bound; g in [0,4)
      int j = jb + g;                              // j <= 59, j+4 <= 63
      bool oka = j < nrem;
      bool okb = j + 4 < nrem;
      int ea = __shfl(idx_l, j);
      int eb = __shfl(idx_l, j + 4);
      float pa_ = ph + pe[ea];
      float pb_ = ph + pe[eb];
      float va = e1[(size_t)ea * 16 + t];
      float vb = e1[(size_t)eb * 16 + t];
      float sa = oka ? (pa_ > 0.f ? pa_ : 0.2f * pa_) : -1e30f;
      float sb = okb ? (pb_ > 0.f ? pb_ : 0.2f * pb_) : -1e30f;
      float mn = fmaxf(m, fmaxf(sa, sb));
      float eo = __expf(m - mn);
      float exa = oka ? __expf(sa - mn) : 0.f;
      float exb = okb ? __expf(sb - mn) : 0.f;
      l = l * eo + exa + exb;
      acc = acc * eo + exa * va + exb * vb;
      m = mn;
    }
  }
#pragma unroll
  for (int d = 16; d < 64; d <<= 1) {
    float mo = __shfl_xor(m, d), lo = __shfl_xor(l, d), ao = __shfl_xor(acc, d);
    float mn = fmaxf(m, mo);
    float ea = __expf(m - mn), eb = __expf(mo - mn);
    l = l * ea + lo * eb;
    acc = acc * ea + ao * eb;
    m = mn;
  }
  float val = acc / (l + 1e-9f);            // H1[wave][t] (empty -> 0, matches ref)
  if (g == 0) H1out[(size_t)wave * 16 + t] = val;
  // fused gemm2: h2 = elu(H1) @ W2, plus layer-2 phv epilogue (round-1 code)
  float x = val > 0.f ? val : expm1f(val);
  float p1 = 0.f, p2 = 0.f, myh2 = 0.f;
#pragma unroll
  for (int j = 0; j < N_CLS; ++j) {
    float term = x * W2[t * N_CLS + j];
#pragma unroll
    for (int d = 1; d < 16; d <<= 1) term += __shfl_xor(term, d);
    p1 += term * a1_2[j];
    p2 += term * a2_2[j];
    if (t == j) myh2 = term;
  }
  if (g == 0) {
    if (t < N_CLS) h2g[(size_t)wave * N_CLS + t] = myh2;
    if (t == 0) phv[wave] = make_float2(p1, p2);
  }
}

// ---------------- node phase 2 (D=7, GROUP=8), round-1 numerics + fused logsm ------
__global__ __launch_bounds__(256) void node2_kernel(
    const float2* __restrict__ phv, const float* __restrict__ e2,
    const float* __restrict__ pe, const int* __restrict__ noff,
    const int* __restrict__ perm_e, float* __restrict__ H2out,
    float* __restrict__ logp) {
  int wave = (blockIdx.x * blockDim.x + threadIdx.x) >> 6;
  int lane = threadIdx.x & 63;
  if (wave >= N_NODES) return;
  int o0 = noff[wave], o1 = noff[wave + 1];
  int g = lane >> 3, t = lane & 7;
  float ph = phv[wave].y;
  float m = -1e30f, l = 0.f, acc = 0.f;
  for (int base = o0; base < o1; base += 64) {
    int nrem = o1 - base; if (nrem > 64) nrem = 64;
    int li = base + lane;
    int idx_l = perm_e[li < o1 ? li : o1 - 1];
    for (int jb = 0; jb < nrem; jb += 16) {       // uniform bound; g in [0,8)
      int j = jb + g;                              // j <= 55, j+8 <= 63
      bool oka = j < nrem;
      bool okb = j + 8 < nrem;
      int ea = __shfl(idx_l, j);
      int eb = __shfl(idx_l, j + 8);
      float pa_ = ph + pe[ea];
      float pb_ = ph + pe[eb];
      float va = (t < N_CLS) ? e2[(size_t)ea * N_CLS + t] : 0.f;
      float vb = (t < N_CLS) ? e2[(size_t)eb * N_CLS + t] : 0.f;
      float sa = oka ? (pa_ > 0.f ? pa_ : 0.2f * pa_) : -1e30f;
      float sb = okb ? (pb_ > 0.f ? pb_ : 0.2f * pb_) : -1e30f;
      float mn = fmaxf(m, fmaxf(sa, sb));
      float eo = __expf(m - mn);
      float exa = oka ? __expf(sa - mn) : 0.f;
      float exb = okb ? __expf(sb - mn) : 0.f;
      l = l * eo + exa + exb;
      acc = acc * eo + exa * va + exb * vb;
      m = mn;
    }
  }
#pragma unroll
  for (int d = 8; d < 64; d <<= 1) {
    float mo = __shfl_xor(m, d), lo = __shfl_xor(l, d), ao = __shfl_xor(acc, d);
    float mn = fmaxf(m, mo);
    float ea = __expf(m - mn), eb = __expf(mo - mn);
    l = l * ea + lo * eb;
    acc = acc * ea + ao * eb;
    m = mn;
  }
  float val = acc / (l + 1e-9f);            // H2[wave][t] (empty -> 0)
  if (g == 0 && t < N_CLS) H2out[(size_t)wave * N_CLS + t] = val;
  // fused log_softmax over 7 classes within each 8-lane group
  float xm = (t < N_CLS) ? val : -1e30f;
#pragma unroll
  for (int d = 1; d < 8; d <<= 1) xm = fmaxf(xm, __shfl_xor(xm, d));
  float se = (t < N_CLS) ? __expf(val - xm) : 0.f;
#pragma unroll
  for (int d = 1; d < 8; d <<= 1) se += __shfl_xor(se, d);
  float lg = logf(se);
  if (g == 0 && t < N_CLS) logp[(size_t)wave * N_CLS + t] = val - xm - lg;
}

// ---------------- launch ----------------
extern "C" void kernel_launch(void* const* d_in, const int* in_sizes, int n_in,
                              void* d_out, int out_size, void* d_ws, size_t ws_size,
                              hipStream_t stream) {
  const float* H    = (const float*)d_in[0];
  const float* W1   = (const float*)d_in[1];
  const float* a1_1 = (const float*)d_in[2];
  const float* a2_1 = (const float*)d_in[3];
  const float* W2   = (const float*)d_in[4];
  const float* a1_2 = (const float*)d_in[5];
  const float* a2_2 = (const float*)d_in[6];
  const int* nidx   = (const int*)d_in[7];
  const int* eidx   = (const int*)d_in[8];

  float* outp = (float*)d_out;
  float* logp = outp;                                   // [N,7]
  float* H1   = outp + (size_t)N_NODES * N_CLS;         // [N,16]
  float* H2   = H1 + (size_t)N_NODES * D_HID;           // [N,7]

  char* ws = (char*)d_ws;
  float* h1g  = (float*)(ws + 0);          //  6,400,000 B : N x 16
  float* e1   = (float*)(ws + 6400000);    //  6,400,000 B : E x 16
  float* h2g  = (float*)(ws + 12800000);   //  2,800,000 B : N x 7
  float* e2   = (float*)(ws + 15600000);   //  2,800,000 B : E x 7
  int* eoff   = (int*)(ws + 18400000);     //    400,004 B : E+1
  int* noff   = (int*)(ws + 18800128);     //    400,004 B : N+1
  float* pe   = (float*)(ws + 19200256);   //    400,000 B : E
  int* perm_e = (int*)(ws + 19600384);     // 12,800,000 B : NNZ
  float2* phv = (float2*)(ws + 32400384);  //    800,000 B : N x {p_a1, p_a2}
  int* gcnt   = (int*)(ws + 33200384);     //      3,128 B : NBK
  int* boff   = (int*)(ws + 33203584);     //      3,132 B : NBK+1
  int* bcur   = (int*)(ws + 33206784);     //      3,128 B : NBK
  int* binned = (int*)(ws + 33210368);     // 12,800,000 B : NNZ

  const int TB = 256;

  hipMemsetAsync(gcnt, 0, NBK * sizeof(int), stream);
  // K1: gemm1 (BW-bound) || hist || eoff
  k1_kernel<<<G_GEMM + G_HIST + G_EOFF, TB, 0, stream>>>(
      H, W1, a1_1, a2_1, h1g, phv, eidx, eoff, nidx, gcnt);
  bscan_kernel<<<1, 1024, 0, stream>>>(gcnt, boff, bcur);
  // K3: bin (needs bscan) || edge phase 1 (needs only K1 outputs)
  k3_kernel<<<G_BIN + 25000, TB, 0, stream>>>(
      nidx, eidx, bcur, binned, h1g, phv, a2_1, eoff, e1, pe);
  csr_kernel<<<NBK, TB, 0, stream>>>(binned, boff, noff, perm_e, N_NODES);
  // node phase 1 + fused gemm2 + layer-2 phv
  node1_kernel<<<25000, TB, 0, stream>>>(phv, e1, pe, noff, perm_e, H1, h2g,
                                         W2, a1_2, a2_2);
  // layer 2
  edge_kernel<N_CLS, 8><<<25000, TB, 0, stream>>>(h2g, phv, a2_2, eoff, nidx, e2, pe, N_EDGESC);
  node2_kernel<<<25000, TB, 0, stream>>>(phv, e2, pe, noff, perm_e, H2, logp);
}

// Round 5
// 622.497 us; speedup vs baseline: 1.1942x; 1.0073x over previous
//
#include <hip/hip_runtime.h>
#include <hip/hip_bf16.h>
#include <math.h>

#define N_NODES 100000
#define N_EDGESC 100000
#define NNZ_C   3200000
#define D_IN    512
#define D_HID   16
#define N_CLS   7
#define NBK     782   // ceil(100000/128) node buckets, bucket = v>>7

// k1 block-range split
#define G_GEMM 1563   // ceil(6250/4) : gemm1, 4 waves/block, 16 rows/wave
#define G_HIST 1000   // 3200 entries each
#define G_EOFF 3125   // 1024 entries each (4 per thread)
// k3 block-range split
#define G_BIN  1000   // 3200 entries each

typedef short short8 __attribute__((ext_vector_type(8)));
typedef float f32x4  __attribute__((ext_vector_type(4)));

__device__ __forceinline__ unsigned short f2bf_rn(float x) {
  unsigned int u = __float_as_uint(x);
  u += 0x7fff + ((u >> 16) & 1);
  return (unsigned short)(u >> 16);
}
__device__ __forceinline__ float bf2f(unsigned short b) {
  return __uint_as_float(((unsigned int)b) << 16);
}

// ---------------- setup bodies ----------------
__device__ __forceinline__ void eoff_body(int b, const int* __restrict__ eidx,
                                          int* __restrict__ eoff) {
  int i0 = (b * 256 + threadIdx.x) * 4;
  if (i0 >= NNZ_C) return;
  int4 v4 = *(const int4*)(eidx + i0);
  int vv[4] = {v4.x, v4.y, v4.z, v4.w};
  int prev = (i0 == 0) ? -1 : eidx[i0 - 1];
#pragma unroll
  for (int k = 0; k < 4; ++k) {
    for (int e = prev + 1; e <= vv[k]; ++e) eoff[e] = i0 + k;
    prev = vv[k];
  }
  if (i0 + 4 == NNZ_C) {
    for (int e = prev + 1; e <= N_EDGESC; ++e) eoff[e] = NNZ_C;
  }
}

__device__ __forceinline__ void hist_body(int b, const int* __restrict__ nidx,
                                          int* __restrict__ gcnt) {
  __shared__ int lh[NBK];
  int t = threadIdx.x;
  for (int i = t; i < NBK; i += 256) lh[i] = 0;
  __syncthreads();
  int base = b * 3200, end = base + 3200;
  for (int i = base + t; i < end; i += 256) atomicAdd(&lh[nidx[i] >> 7], 1);
  __syncthreads();
  for (int i = t; i < NBK; i += 256) {
    int c = lh[i];
    if (c) atomicAdd(&gcnt[i], c);
  }
}

__device__ __forceinline__ void bin_body(int b, const int* __restrict__ nidx,
                                         const int* __restrict__ eidx,
                                         int* __restrict__ bcur, int* __restrict__ binned) {
  __shared__ int lh[NBK];
  __shared__ int gb[NBK];
  int t = threadIdx.x;
  for (int i = t; i < NBK; i += 256) lh[i] = 0;
  __syncthreads();
  int base = b * 3200, end = base + 3200;
  for (int i = base + t; i < end; i += 256) atomicAdd(&lh[nidx[i] >> 7], 1);
  __syncthreads();
  for (int i = t; i < NBK; i += 256) {
    int c = lh[i];
    gb[i] = c ? atomicAdd(&bcur[i], c) : 0;
    lh[i] = 0;
  }
  __syncthreads();
  for (int i = base + t; i < end; i += 256) {
    int v = nidx[i], e = eidx[i];
    int bk = v >> 7;
    int r = atomicAdd(&lh[bk], 1);
    binned[gb[bk] + r] = e | ((v & 127) << 20);
  }
}

// ---------------- setup: scan bucket counts -> boff, init bcur ----------------
__global__ void bscan_kernel(const int* __restrict__ gcnt, int* __restrict__ boff,
                             int* __restrict__ bcur) {
  __shared__ int lds[1024];
  int t = threadIdx.x;
  int v = (t < NBK) ? gcnt[t] : 0;
  lds[t] = v;
  __syncthreads();
  for (int d = 1; d < 1024; d <<= 1) {
    int u = (t >= d) ? lds[t - d] : 0;
    __syncthreads();
    lds[t] += u;
    __syncthreads();
  }
  if (t < NBK) {
    boff[t + 1] = lds[t];
    bcur[t] = lds[t] - v;   // exclusive
  }
  if (t == 0) boff[0] = 0;
}

// ---------------- setup: per-bucket node-CSR (noff + perm_e) ----------------
__global__ void csr_kernel(const int* __restrict__ binned, const int* __restrict__ boff,
                           int* __restrict__ noff, int* __restrict__ perm_e, int N) {
  __shared__ int lh[128];
  __shared__ int lsc[128];
  __shared__ int lcur[128];
  int b = blockIdx.x;
  int t = threadIdx.x;
  int s = boff[b], e = boff[b + 1];
  if (t < 128) lh[t] = 0;
  __syncthreads();
  for (int i = s + t; i < e; i += 256) {
    atomicAdd(&lh[binned[i] >> 20], 1);
  }
  __syncthreads();
  if (t < 128) lsc[t] = lh[t];
  __syncthreads();
  for (int d = 1; d < 128; d <<= 1) {
    int u = (t < 128 && t >= d) ? lsc[t - d] : 0;
    __syncthreads();
    if (t < 128) lsc[t] += u;
    __syncthreads();
  }
  if (t < 128) {
    int excl = lsc[t] - lh[t];
    lcur[t] = excl;
    int n = b * 128 + t;
    if (n <= N) noff[n] = s + excl;
  }
  __syncthreads();
  for (int i = s + t; i < e; i += 256) {
    int p = binned[i];
    int r = atomicAdd(&lcur[p >> 20], 1);
    perm_e[s + r] = p & 0xFFFFF;
  }
}

// ---------------- GEMM1 body via MFMA (bf16 3-term split), depth-4 prefetch ring ----
__device__ __forceinline__ void gemm1_body(int b,
    const float* __restrict__ X, const float* __restrict__ W,
    const float* __restrict__ a1, const float* __restrict__ a2,
    float* __restrict__ Hout, float2* __restrict__ phv) {
  int wid = b * 4 + (threadIdx.x >> 6);
  if (wid >= 6250) return;
  int lane = threadIdx.x & 63;
  int col  = lane & 15;
  int quad = lane >> 4;

  short8 wh[16], wl[16];
#pragma unroll
  for (int c = 0; c < 16; ++c) {
#pragma unroll
    for (int j = 0; j < 8; ++j) {
      float w = W[(c * 32 + quad * 8 + j) * 16 + col];
      unsigned short h = f2bf_rn(w);
      wh[c][j] = (short)h;
      wl[c][j] = (short)f2bf_rn(w - bf2f(h));
    }
  }

  int rowbase = wid * 16;
  const float4* Xr = (const float4*)(X + (size_t)(rowbase + col) * D_IN) + quad * 2;

  f32x4 acc_hh = {0.f, 0.f, 0.f, 0.f};
  f32x4 acc_hl = {0.f, 0.f, 0.f, 0.f};
  f32x4 acc_lh = {0.f, 0.f, 0.f, 0.f};

  float4 pre[4][2];
#pragma unroll
  for (int q = 0; q < 4; ++q) { pre[q][0] = Xr[q * 8]; pre[q][1] = Xr[q * 8 + 1]; }
#pragma unroll
  for (int c = 0; c < 16; ++c) {
    float4 u0 = pre[c & 3][0], u1 = pre[c & 3][1];
    if (c < 12) { pre[c & 3][0] = Xr[(c + 4) * 8]; pre[c & 3][1] = Xr[(c + 4) * 8 + 1]; }
    float xs[8] = {u0.x, u0.y, u0.z, u0.w, u1.x, u1.y, u1.z, u1.w};
    short8 ah, al;
#pragma unroll
    for (int j = 0; j < 8; ++j) {
      unsigned short h = f2bf_rn(xs[j]);
      ah[j] = (short)h;
      al[j] = (short)f2bf_rn(xs[j] - bf2f(h));
    }
    acc_hh = __builtin_amdgcn_mfma_f32_16x16x32_bf16(ah, wh[c], acc_hh, 0, 0, 0);
    acc_hl = __builtin_amdgcn_mfma_f32_16x16x32_bf16(ah, wl[c], acc_hl, 0, 0, 0);
    acc_lh = __builtin_amdgcn_mfma_f32_16x16x32_bf16(al, wh[c], acc_lh, 0, 0, 0);
  }

  float a1c = a1[col], a2c = a2[col];
#pragma unroll
  for (int r = 0; r < 4; ++r) {
    float v = acc_hh[r] + acc_hl[r] + acc_lh[r];
    int row = rowbase + quad * 4 + r;
    Hout[(size_t)row * 16 + col] = v;
    float p1 = v * a1c, p2 = v * a2c;
#pragma unroll
    for (int d = 1; d < 16; d <<= 1) { p1 += __shfl_xor(p1, d); p2 += __shfl_xor(p2, d); }
    if (col == 0) phv[row] = make_float2(p1, p2);
  }
}

// ---------------- K1: gemm1 || hist || eoff ----------------
__global__ __launch_bounds__(256) void k1_kernel(
    const float* __restrict__ X, const float* __restrict__ W1,
    const float* __restrict__ a1_1, const float* __restrict__ a2_1,
    float* __restrict__ Hout, float2* __restrict__ phv,
    const int* __restrict__ eidx, int* __restrict__ eoff,
    const int* __restrict__ nidx, int* __restrict__ gcnt) {
  int b = blockIdx.x;
  if (b < G_GEMM) {
    gemm1_body(b, X, W1, a1_1, a2_1, Hout, phv);
  } else if (b < G_GEMM + G_HIST) {
    hist_body(b - G_GEMM, nidx, gcnt);
  } else {
    eoff_body(b - G_GEMM - G_HIST, eidx, eoff);
  }
}

// ---------------- edge phase 1 (D=16, GROUP=16): 4-wide online softmax.
// Uniform inner trip count (bound depends only on nrem); validity predicated by
// value (s=-1e30, weight 0). All shfl sources active, positions <= 63.
__device__ __forceinline__ void edge1_body(
    const float* __restrict__ h, const float2* __restrict__ phv,
    const float* __restrict__ a2, const int* __restrict__ eoff,
    const int* __restrict__ nidx, float* __restrict__ eout,
    float* __restrict__ pe, int wave, int lane) {
  if (wave >= N_EDGESC) return;
  int o0 = eoff[wave], o1 = eoff[wave + 1];
  int g = lane >> 4, t = lane & 15;
  if (o0 == o1) {
    if (g == 0) {
      eout[(size_t)wave * 16 + t] = 0.f;
      if (t == 0) pe[wave] = 0.f;
    }
    return;
  }
  float m = -1e30f, l = 0.f, acc = 0.f;
  for (int base = o0; base < o1; base += 64) {
    int nrem = o1 - base; if (nrem > 64) nrem = 64;
    int li = base + lane;
    int idx_l = nidx[li < o1 ? li : o1 - 1];
    for (int jb = 0; jb < nrem; jb += 16) {   // uniform bound; g in [0,4)
      int j = jb + g;                          // j+12 <= 63
      bool ok0 = j < nrem, ok1 = j + 4 < nrem, ok2 = j + 8 < nrem, ok3 = j + 12 < nrem;
      int v0 = __shfl(idx_l, j);
      int v1 = __shfl(idx_l, j + 4);
      int v2 = __shfl(idx_l, j + 8);
      int v3 = __shfl(idx_l, j + 12);
      float P0 = phv[v0].x, P1 = phv[v1].x, P2 = phv[v2].x, P3 = phv[v3].x;
      float h0 = h[(size_t)v0 * 16 + t];
      float h1 = h[(size_t)v1 * 16 + t];
      float h2 = h[(size_t)v2 * 16 + t];
      float h3 = h[(size_t)v3 * 16 + t];
      float s0 = ok0 ? (P0 > 0.f ? P0 : 0.2f * P0) : -1e30f;
      float s1 = ok1 ? (P1 > 0.f ? P1 : 0.2f * P1) : -1e30f;
      float s2 = ok2 ? (P2 > 0.f ? P2 : 0.2f * P2) : -1e30f;
      float s3 = ok3 ? (P3 > 0.f ? P3 : 0.2f * P3) : -1e30f;
      float mn = fmaxf(fmaxf(m, fmaxf(s0, s1)), fmaxf(s2, s3));
      float eo = __expf(m - mn);
      float e0 = ok0 ? __expf(s0 - mn) : 0.f;
      float e1 = ok1 ? __expf(s1 - mn) : 0.f;
      float e2 = ok2 ? __expf(s2 - mn) : 0.f;
      float e3 = ok3 ? __expf(s3 - mn) : 0.f;
      l = l * eo + ((e0 + e1) + (e2 + e3));
      acc = acc * eo + ((e0 * h0 + e1 * h1) + (e2 * h2 + e3 * h3));
      m = mn;
    }
  }
#pragma unroll
  for (int d = 16; d < 64; d <<= 1) {
    float mo = __shfl_xor(m, d), lo = __shfl_xor(l, d), ao = __shfl_xor(acc, d);
    float mn = fmaxf(m, mo);
    float ea = __expf(m - mn), eb = __expf(mo - mn);
    l = l * ea + lo * eb;
    acc = acc * ea + ao * eb;
    m = mn;
  }
  float val = acc / (l + 1e-9f);
  float pav = val * a2[16 + t];
#pragma unroll
  for (int d = 1; d < 16; d <<= 1) pav += __shfl_xor(pav, d);
  if (g == 0) {
    eout[(size_t)wave * 16 + t] = val;
    if (t == 0) pe[wave] = pav;
  }
}

// ---------------- K3: bin || edge1 ----------------
__global__ __launch_bounds__(256) void k3_kernel(
    const int* __restrict__ nidx, const int* __restrict__ eidx,
    int* __restrict__ bcur, int* __restrict__ binned,
    const float* __restrict__ h1g, const float2* __restrict__ phv,
    const float* __restrict__ a2_1, const int* __restrict__ eoff,
    float* __restrict__ e1, float* __restrict__ pe) {
  int b = blockIdx.x;
  if (b < G_BIN) {
    bin_body(b, nidx, eidx, bcur, binned);
  } else {
    int wave = (b - G_BIN) * 4 + (threadIdx.x >> 6);
    edge1_body(h1g, phv, a2_1, eoff, nidx, e1, pe, wave, threadIdx.x & 63);
  }
}

// ---------------- node phase 1 (D=16), 4-wide + fused gemm2 (packed h2g8) --------
__global__ __launch_bounds__(256) void node1_kernel(
    const float2* __restrict__ phv, const float* __restrict__ e1,
    const float* __restrict__ pe, const int* __restrict__ noff,
    const int* __restrict__ perm_e, float* __restrict__ H1out,
    float* __restrict__ h2g8, const float* __restrict__ W2,
    const float* __restrict__ a1_2, const float* __restrict__ a2_2,
    float* __restrict__ pn2) {
  int wave = (blockIdx.x * blockDim.x + threadIdx.x) >> 6;
  int lane = threadIdx.x & 63;
  if (wave >= N_NODES) return;
  int o0 = noff[wave], o1 = noff[wave + 1];
  int g = lane >> 4, t = lane & 15;
  float ph = phv[wave].y;
  float m = -1e30f, l = 0.f, acc = 0.f;
  for (int base = o0; base < o1; base += 64) {
    int nrem = o1 - base; if (nrem > 64) nrem = 64;
    int li = base + lane;
    int idx_l = perm_e[li < o1 ? li : o1 - 1];
    for (int jb = 0; jb < nrem; jb += 16) {   // uniform bound; g in [0,4)
      int j = jb + g;                          // j+12 <= 63
      bool ok0 = j < nrem, ok1 = j + 4 < nrem, ok2 = j + 8 < nrem, ok3 = j + 12 < nrem;
      int E0 = __shfl(idx_l, j);
      int E1 = __shfl(idx_l, j + 4);
      int E2 = __shfl(idx_l, j + 8);
      int E3 = __shfl(idx_l, j + 12);
      float P0 = ph + pe[E0], P1 = ph + pe[E1], P2 = ph + pe[E2], P3 = ph + pe[E3];
      float h0 = e1[(size_t)E0 * 16 + t];
      float h1 = e1[(size_t)E1 * 16 + t];
      float h2 = e1[(size_t)E2 * 16 + t];
      float h3 = e1[(size_t)E3 * 16 + t];
      float s0 = ok0 ? (P0 > 0.f ? P0 : 0.2f * P0) : -1e30f;
      float s1 = ok1 ? (P1 > 0.f ? P1 : 0.2f * P1) : -1e30f;
      float s2 = ok2 ? (P2 > 0.f ? P2 : 0.2f * P2) : -1e30f;
      float s3 = ok3 ? (P3 > 0.f ? P3 : 0.2f * P3) : -1e30f;
      float mn = fmaxf(fmaxf(m, fmaxf(s0, s1)), fmaxf(s2, s3));
      float eo = __expf(m - mn);
      float e0 = ok0 ? __expf(s0 - mn) : 0.f;
      float e1x = ok1 ? __expf(s1 - mn) : 0.f;
      float e2x = ok2 ? __expf(s2 - mn) : 0.f;
      float e3x = ok3 ? __expf(s3 - mn) : 0.f;
      l = l * eo + ((e0 + e1x) + (e2x + e3x));
      acc = acc * eo + ((e0 * h0 + e1x * h1) + (e2x * h2 + e3x * h3));
      m = mn;
    }
  }
#pragma unroll
  for (int d = 16; d < 64; d <<= 1) {
    float mo = __shfl_xor(m, d), lo = __shfl_xor(l, d), ao = __shfl_xor(acc, d);
    float ea_, eb_;
    float mn = fmaxf(m, mo);
    ea_ = __expf(m - mn); eb_ = __expf(mo - mn);
    l = l * ea_ + lo * eb_;
    acc = acc * ea_ + ao * eb_;
    m = mn;
  }
  float val = acc / (l + 1e-9f);            // H1[wave][t] (empty -> 0, matches ref)
  if (g == 0) H1out[(size_t)wave * 16 + t] = val;
  // fused gemm2: h2 = elu(H1) @ W2; pack row8 = [h2[0..6], p1]; pn2 = h2 . a2_2
  float x = val > 0.f ? val : expm1f(val);
  float p1 = 0.f, p2s = 0.f, myh2 = 0.f;
#pragma unroll
  for (int j = 0; j < N_CLS; ++j) {
    float term = x * W2[t * N_CLS + j];
#pragma unroll
    for (int d = 1; d < 16; d <<= 1) term += __shfl_xor(term, d);
    p1 += term * a1_2[j];
    p2s += term * a2_2[j];
    if (t == j) myh2 = term;
  }
  if (g == 0) {
    if (t < N_CLS) h2g8[(size_t)wave * 8 + t] = myh2;
    if (t == 7) h2g8[(size_t)wave * 8 + 7] = p1;
    if (t == 0) pn2[wave] = p2s;
  }
}

// ---------------- edge phase 2 (GROUP=8, packed rows [7 vals, score]) ----------------
__global__ __launch_bounds__(256) void edge2_kernel(
    const float* __restrict__ h2g8, const int* __restrict__ eoff,
    const int* __restrict__ nidx, const float* __restrict__ a2_2,
    float* __restrict__ e28) {
  int wave = (blockIdx.x * blockDim.x + threadIdx.x) >> 6;
  int lane = threadIdx.x & 63;
  if (wave >= N_EDGESC) return;
  int o0 = eoff[wave], o1 = eoff[wave + 1];
  int g = lane >> 3, t = lane & 7;
  if (o0 == o1) {
    if (g == 0) e28[(size_t)wave * 8 + t] = 0.f;   // vals + pe all zero
    return;
  }
  float m = -1e30f, l = 0.f, acc = 0.f;
  for (int base = o0; base < o1; base += 64) {
    int nrem = o1 - base; if (nrem > 64) nrem = 64;
    int li = base + lane;
    int idx_l = nidx[li < o1 ? li : o1 - 1];
    for (int jb = 0; jb < nrem; jb += 32) {   // uniform bound; g in [0,8)
      int j = jb + g;                          // j+24 <= 63
      bool ok0 = j < nrem, ok1 = j + 8 < nrem, ok2 = j + 16 < nrem, ok3 = j + 24 < nrem;
      int v0 = __shfl(idx_l, j);
      int v1 = __shfl(idx_l, j + 8);
      int v2 = __shfl(idx_l, j + 16);
      int v3 = __shfl(idx_l, j + 24);
      float f0 = h2g8[(size_t)v0 * 8 + t];
      float f1 = h2g8[(size_t)v1 * 8 + t];
      float f2 = h2g8[(size_t)v2 * 8 + t];
      float f3 = h2g8[(size_t)v3 * 8 + t];
      // slot 7 carries p1 = h2 . a1_2 ; broadcast within the 8-lane group
      float P0 = __shfl(f0, lane | 7);
      float P1 = __shfl(f1, lane | 7);
      float P2 = __shfl(f2, lane | 7);
      float P3 = __shfl(f3, lane | 7);
      float h0 = (t < 7) ? f0 : 0.f;
      float h1 = (t < 7) ? f1 : 0.f;
      float h2v = (t < 7) ? f2 : 0.f;
      float h3 = (t < 7) ? f3 : 0.f;
      float s0 = ok0 ? (P0 > 0.f ? P0 : 0.2f * P0) : -1e30f;
      float s1 = ok1 ? (P1 > 0.f ? P1 : 0.2f * P1) : -1e30f;
      float s2 = ok2 ? (P2 > 0.f ? P2 : 0.2f * P2) : -1e30f;
      float s3 = ok3 ? (P3 > 0.f ? P3 : 0.2f * P3) : -1e30f;
      float mn = fmaxf(fmaxf(m, fmaxf(s0, s1)), fmaxf(s2, s3));
      float eo = __expf(m - mn);
      float e0 = ok0 ? __expf(s0 - mn) : 0.f;
      float e1 = ok1 ? __expf(s1 - mn) : 0.f;
      float e2 = ok2 ? __expf(s2 - mn) : 0.f;
      float e3 = ok3 ? __expf(s3 - mn) : 0.f;
      l = l * eo + ((e0 + e1) + (e2 + e3));
      acc = acc * eo + ((e0 * h0 + e1 * h1) + (e2 * h2v + e3 * h3));
      m = mn;
    }
  }
#pragma unroll
  for (int d = 8; d < 64; d <<= 1) {
    float mo = __shfl_xor(m, d), lo = __shfl_xor(l, d), ao = __shfl_xor(acc, d);
    float mn = fmaxf(m, mo);
    float ea = __expf(m - mn), eb = __expf(mo - mn);
    l = l * ea + lo * eb;
    acc = acc * ea + ao * eb;
    m = mn;
  }
  float val = acc / (l + 1e-9f);
  float pav = (t < 7) ? val * a2_2[7 + t] : 0.f;
#pragma unroll
  for (int d = 1; d < 8; d <<= 1) pav += __shfl_xor(pav, d);
  if (g == 0) e28[(size_t)wave * 8 + t] = (t < 7) ? val : pav;   // slot 7 = pe
}

// ---------------- node phase 2 (GROUP=8, packed rows) + fused log_softmax ----------
__global__ __launch_bounds__(256) void node2_kernel(
    const float* __restrict__ e28, const float* __restrict__ pn2,
    const int* __restrict__ noff, const int* __restrict__ perm_e,
    float* __restrict__ H2out, float* __restrict__ logp) {
  int wave = (blockIdx.x * blockDim.x + threadIdx.x) >> 6;
  int lane = threadIdx.x & 63;
  if (wave >= N_NODES) return;
  int o0 = noff[wave], o1 = noff[wave + 1];
  int g = lane >> 3, t = lane & 7;
  float ph = pn2[wave];
  float m = -1e30f, l = 0.f, acc = 0.f;
  for (int base = o0; base < o1; base += 64) {
    int nrem = o1 - base; if (nrem > 64) nrem = 64;
    int li = base + lane;
    int idx_l = perm_e[li < o1 ? li : o1 - 1];
    for (int jb = 0; jb < nrem; jb += 32) {   // uniform bound; g in [0,8)
      int j = jb + g;                          // j+24 <= 63
      bool ok0 = j < nrem, ok1 = j + 8 < nrem, ok2 = j + 16 < nrem, ok3 = j + 24 < nrem;
      int E0 = __shfl(idx_l, j);
      int E1 = __shfl(idx_l, j + 8);
      int E2 = __shfl(idx_l, j + 16);
      int E3 = __shfl(idx_l, j + 24);
      float f0 = e28[(size_t)E0 * 8 + t];
      float f1 = e28[(size_t)E1 * 8 + t];
      float f2 = e28[(size_t)E2 * 8 + t];
      float f3 = e28[(size_t)E3 * 8 + t];
      // slot 7 carries pe; broadcast within group
      float P0 = ph + __shfl(f0, lane | 7);
      float P1 = ph + __shfl(f1, lane | 7);
      float P2 = ph + __shfl(f2, lane | 7);
      float P3 = ph + __shfl(f3, lane | 7);
      float h0 = (t < 7) ? f0 : 0.f;
      float h1 = (t < 7) ? f1 : 0.f;
      float h2v = (t < 7) ? f2 : 0.f;
      float h3 = (t < 7) ? f3 : 0.f;
      float s0 = ok0 ? (P0 > 0.f ? P0 : 0.2f * P0) : -1e30f;
      float s1 = ok1 ? (P1 > 0.f ? P1 : 0.2f * P1) : -1e30f;
      float s2 = ok2 ? (P2 > 0.f ? P2 : 0.2f * P2) : -1e30f;
      float s3 = ok3 ? (P3 > 0.f ? P3 : 0.2f * P3) : -1e30f;
      float mn = fmaxf(fmaxf(m, fmaxf(s0, s1)), fmaxf(s2, s3));
      float eo = __expf(m - mn);
      float e0 = ok0 ? __expf(s0 - mn) : 0.f;
      float e1 = ok1 ? __expf(s1 - mn) : 0.f;
      float e2 = ok2 ? __expf(s2 - mn) : 0.f;
      float e3 = ok3 ? __expf(s3 - mn) : 0.f;
      l = l * eo + ((e0 + e1) + (e2 + e3));
      acc = acc * eo + ((e0 * h0 + e1 * h1) + (e2 * h2v + e3 * h3));
      m = mn;
    }
  }
#pragma unroll
  for (int d = 8; d < 64; d <<= 1) {
    float mo = __shfl_xor(m, d), lo = __shfl_xor(l, d), ao = __shfl_xor(acc, d);
    float mn = fmaxf(m, mo);
    float ea = __expf(m - mn), eb = __expf(mo - mn);
    l = l * ea + lo * eb;
    acc = acc * ea + ao * eb;
    m = mn;
  }
  float val = acc / (l + 1e-9f);            // H2[wave][t] (empty -> 0)
  if (g == 0 && t < 7) H2out[(size_t)wave * 7 + t] = val;
  // fused log_softmax over 7 classes within each 8-lane group
  float xm = (t < 7) ? val : -1e30f;
#pragma unroll
  for (int d = 1; d < 8; d <<= 1) xm = fmaxf(xm, __shfl_xor(xm, d));
  float se = (t < 7) ? __expf(val - xm) : 0.f;
#pragma unroll
  for (int d = 1; d < 8; d <<= 1) se += __shfl_xor(se, d);
  float lg = logf(se);
  if (g == 0 && t < 7) logp[(size_t)wave * 7 + t] = val - xm - lg;
}

// ---------------- launch ----------------
extern "C" void kernel_launch(void* const* d_in, const int* in_sizes, int n_in,
                              void* d_out, int out_size, void* d_ws, size_t ws_size,
                              hipStream_t stream) {
  const float* H    = (const float*)d_in[0];
  const float* W1   = (const float*)d_in[1];
  const float* a1_1 = (const float*)d_in[2];
  const float* a2_1 = (const float*)d_in[3];
  const float* W2   = (const float*)d_in[4];
  const float* a1_2 = (const float*)d_in[5];
  const float* a2_2 = (const float*)d_in[6];
  const int* nidx   = (const int*)d_in[7];
  const int* eidx   = (const int*)d_in[8];

  float* outp = (float*)d_out;
  float* logp = outp;                                   // [N,7]
  float* H1   = outp + (size_t)N_NODES * N_CLS;         // [N,16]
  float* H2   = H1 + (size_t)N_NODES * D_HID;           // [N,7]

  char* ws = (char*)d_ws;
  float* h1g  = (float*)(ws + 0);          //  6,400,000 B : N x 16
  float* e1   = (float*)(ws + 6400000);    //  6,400,000 B : E x 16
  float* h2g8 = (float*)(ws + 12800000);   //  3,200,000 B : N x 8 [h2|p1]
  float* e28  = (float*)(ws + 16000000);   //  3,200,000 B : E x 8 [e2|pe]
  int* eoff   = (int*)(ws + 19200000);     //    400,004 B : E+1
  int* noff   = (int*)(ws + 19600128);     //    400,004 B : N+1
  float* pe   = (float*)(ws + 20000256);   //    400,000 B : E
  float* pn2  = (float*)(ws + 20400256);   //    400,000 B : N (h2 . a2_2)
  float2* phv = (float2*)(ws + 20800256);  //    800,000 B : N x {p_a1, p_a2}
  int* perm_e = (int*)(ws + 21600256);     // 12,800,000 B : NNZ
  int* gcnt   = (int*)(ws + 34400256);     //      3,128 B : NBK
  int* boff   = (int*)(ws + 34403456);     //      3,132 B : NBK+1
  int* bcur   = (int*)(ws + 34406656);     //      3,128 B : NBK
  int* binned = (int*)(ws + 34409856);     // 12,800,000 B : NNZ

  const int TB = 256;

  hipMemsetAsync(gcnt, 0, NBK * sizeof(int), stream);
  // K1: gemm1 (BW-bound) || hist || eoff
  k1_kernel<<<G_GEMM + G_HIST + G_EOFF, TB, 0, stream>>>(
      H, W1, a1_1, a2_1, h1g, phv, eidx, eoff, nidx, gcnt);
  bscan_kernel<<<1, 1024, 0, stream>>>(gcnt, boff, bcur);
  // K3: bin (needs bscan) || edge phase 1 (needs only K1 outputs)
  k3_kernel<<<G_BIN + 25000, TB, 0, stream>>>(
      nidx, eidx, bcur, binned, h1g, phv, a2_1, eoff, e1, pe);
  csr_kernel<<<NBK, TB, 0, stream>>>(binned, boff, noff, perm_e, N_NODES);
  // node phase 1 + fused gemm2 (packed h2g8) + pn2
  node1_kernel<<<25000, TB, 0, stream>>>(phv, e1, pe, noff, perm_e, H1, h2g8,
                                         W2, a1_2, a2_2, pn2);
  // layer 2 (packed rows)
  edge2_kernel<<<25000, TB, 0, stream>>>(h2g8, eoff, nidx, a2_2, e28);
  node2_kernel<<<25000, TB, 0, stream>>>(e28, pn2, noff, perm_e, H2, logp);
}

// Round 6
// 597.419 us; speedup vs baseline: 1.2444x; 1.0420x over previous
//
#include <hip/hip_runtime.h>
#include <hip/hip_bf16.h>
#include <math.h>

#define N_NODES 100000
#define N_EDGESC 100000
#define NNZ_C   3200000
#define D_IN    512
#define D_HID   16
#define N_CLS   7
#define NBK     782   // ceil(100000/128) node buckets, bucket = v>>7

// k1 block-range split
#define G_GEMM 1563   // ceil(100000/64) : gemm1, 4 waves/block, 64 rows/block
#define G_HIST 1000   // 3200 entries each
#define G_EOFF 3125   // 1024 entries each (4 per thread)
// k3 block-range split
#define G_BIN  125    // 25600 entries each -> ~33-entry runs per (block,bucket)
#define BIN_PER 25600

typedef short short8 __attribute__((ext_vector_type(8)));
typedef float f32x4  __attribute__((ext_vector_type(4)));

__device__ __forceinline__ unsigned short f2bf_rn(float x) {
  unsigned int u = __float_as_uint(x);
  u += 0x7fff + ((u >> 16) & 1);
  return (unsigned short)(u >> 16);
}
__device__ __forceinline__ float bf2f(unsigned short b) {
  return __uint_as_float(((unsigned int)b) << 16);
}

// ---------------- setup bodies ----------------
__device__ __forceinline__ void eoff_body(int b, const int* __restrict__ eidx,
                                          int* __restrict__ eoff) {
  int i0 = (b * 256 + threadIdx.x) * 4;
  if (i0 >= NNZ_C) return;
  int4 v4 = *(const int4*)(eidx + i0);
  int vv[4] = {v4.x, v4.y, v4.z, v4.w};
  int prev = (i0 == 0) ? -1 : eidx[i0 - 1];
#pragma unroll
  for (int k = 0; k < 4; ++k) {
    for (int e = prev + 1; e <= vv[k]; ++e) eoff[e] = i0 + k;
    prev = vv[k];
  }
  if (i0 + 4 == NNZ_C) {
    for (int e = prev + 1; e <= N_EDGESC; ++e) eoff[e] = NNZ_C;
  }
}

__device__ __forceinline__ void hist_body(int b, const int* __restrict__ nidx,
                                          int* __restrict__ gcnt) {
  __shared__ int lh[NBK];
  int t = threadIdx.x;
  for (int i = t; i < NBK; i += 256) lh[i] = 0;
  __syncthreads();
  int base = b * 3200, end = base + 3200;
  for (int i = base + t; i < end; i += 256) atomicAdd(&lh[nidx[i] >> 7], 1);
  __syncthreads();
  for (int i = t; i < NBK; i += 256) {
    int c = lh[i];
    if (c) atomicAdd(&gcnt[i], c);
  }
}

__device__ __forceinline__ void bin_body(int b, const int* __restrict__ nidx,
                                         const int* __restrict__ eidx,
                                         int* __restrict__ bcur, int* __restrict__ binned) {
  __shared__ int lh[NBK];
  __shared__ int gb[NBK];
  int t = threadIdx.x;
  for (int i = t; i < NBK; i += 256) lh[i] = 0;
  __syncthreads();
  int base = b * BIN_PER, end = base + BIN_PER;
  if (end > NNZ_C) end = NNZ_C;
  for (int i = base + t; i < end; i += 256) atomicAdd(&lh[nidx[i] >> 7], 1);
  __syncthreads();
  for (int i = t; i < NBK; i += 256) {
    int c = lh[i];
    gb[i] = c ? atomicAdd(&bcur[i], c) : 0;
    lh[i] = 0;
  }
  __syncthreads();
  for (int i = base + t; i < end; i += 256) {
    int v = nidx[i], e = eidx[i];
    int bk = v >> 7;
    int r = atomicAdd(&lh[bk], 1);
    binned[gb[bk] + r] = e | ((v & 127) << 20);
  }
}

// ---------------- setup: scan bucket counts -> boff, init bcur ----------------
__global__ void bscan_kernel(const int* __restrict__ gcnt, int* __restrict__ boff,
                             int* __restrict__ bcur) {
  __shared__ int lds[1024];
  int t = threadIdx.x;
  int v = (t < NBK) ? gcnt[t] : 0;
  lds[t] = v;
  __syncthreads();
  for (int d = 1; d < 1024; d <<= 1) {
    int u = (t >= d) ? lds[t - d] : 0;
    __syncthreads();
    lds[t] += u;
    __syncthreads();
  }
  if (t < NBK) {
    boff[t + 1] = lds[t];
    bcur[t] = lds[t] - v;   // exclusive
  }
  if (t == 0) boff[0] = 0;
}

// ---------------- setup: per-bucket node-CSR (noff + perm_e) ----------------
__global__ void csr_kernel(const int* __restrict__ binned, const int* __restrict__ boff,
                           int* __restrict__ noff, int* __restrict__ perm_e, int N) {
  __shared__ int lh[128];
  __shared__ int lsc[128];
  __shared__ int lcur[128];
  int b = blockIdx.x;
  int t = threadIdx.x;
  int s = boff[b], e = boff[b + 1];
  if (t < 128) lh[t] = 0;
  __syncthreads();
  for (int i = s + t; i < e; i += 256) {
    atomicAdd(&lh[binned[i] >> 20], 1);
  }
  __syncthreads();
  if (t < 128) lsc[t] = lh[t];
  __syncthreads();
  for (int d = 1; d < 128; d <<= 1) {
    int u = (t < 128 && t >= d) ? lsc[t - d] : 0;
    __syncthreads();
    if (t < 128) lsc[t] += u;
    __syncthreads();
  }
  if (t < 128) {
    int excl = lsc[t] - lh[t];
    lcur[t] = excl;
    int n = b * 128 + t;
    if (n <= N) noff[n] = s + excl;
  }
  __syncthreads();
  for (int i = s + t; i < e; i += 256) {
    int p = binned[i];
    int r = atomicAdd(&lcur[p >> 20], 1);
    perm_e[s + r] = p & 0xFFFFF;
  }
}

// ---------------- GEMM1 via MFMA (bf16 3-term split), LDS-staged X ----------------
// Block = 4 waves = 64 rows. Per K-chunk (32 floats) the block stages 64x128B of X
// with fully-coalesced 128B-per-row global reads (8 threads/row, reg-staged, double
// buffered). LDS layout is piece-major sX[buf][piece(16B)][row*4] -> 16B-aligned
// ds_read_b128, conflict-free-equivalent. MFMA inputs are bitwise-identical to the
// previous direct-load version; only the load path changed.
__device__ __forceinline__ void gemm1_body(int b,
    const float* __restrict__ X, const float* __restrict__ W,
    const float* __restrict__ a1, const float* __restrict__ a2,
    float* __restrict__ Hout, float2* __restrict__ phv) {
  __shared__ __align__(16) float sX[2][8][256];   // 16 KB
  int tid  = threadIdx.x;
  int w    = tid >> 6;
  int lane = tid & 63;
  int col  = lane & 15;
  int quad = lane >> 4;
  int row0 = b * 64;

  // W fragments (hi+lo), identical to before
  short8 wh[16], wl[16];
#pragma unroll
  for (int c = 0; c < 16; ++c) {
#pragma unroll
    for (int j = 0; j < 8; ++j) {
      float wv = W[(c * 32 + quad * 8 + j) * 16 + col];
      unsigned short h = f2bf_rn(wv);
      wh[c][j] = (short)h;
      wl[c][j] = (short)f2bf_rn(wv - bf2f(h));
    }
  }

  // staging helpers: thread covers slot s = k*256+tid -> row r=s>>3, piece o=s&7
  int r0s = (tid >> 3), o0s = tid & 7;          // k=0 slot
  int r1s = ((256 + tid) >> 3), o1s = tid & 7;  // k=1 slot (r1s = r0s+32)
  int rsrc0 = row0 + r0s; if (rsrc0 > N_NODES - 1) rsrc0 = N_NODES - 1;
  int rsrc1 = row0 + r1s; if (rsrc1 > N_NODES - 1) rsrc1 = N_NODES - 1;
  const float* src0 = X + (size_t)rsrc0 * D_IN + o0s * 4;
  const float* src1 = X + (size_t)rsrc1 * D_IN + o1s * 4;

  f32x4 acc_hh = {0.f, 0.f, 0.f, 0.f};
  f32x4 acc_hl = {0.f, 0.f, 0.f, 0.f};
  f32x4 acc_lh = {0.f, 0.f, 0.f, 0.f};

  int rl = (w << 4) + col;          // LDS row 0..63
  int p0 = quad << 1, p1 = p0 + 1;  // 16B pieces of this lane's k-range

  // prologue: stage chunk 0
  float4 va = *(const float4*)(src0);
  float4 vb = *(const float4*)(src1);
  *(float4*)&sX[0][o0s][r0s * 4] = va;
  *(float4*)&sX[0][o1s][r1s * 4] = vb;

#pragma unroll
  for (int c = 0; c < 16; ++c) {
    int cur = c & 1;
    if (c < 15) {                    // load chunk c+1 into registers (early issue)
      va = *(const float4*)(src0 + (c + 1) * 32);
      vb = *(const float4*)(src1 + (c + 1) * 32);
    }
    __syncthreads();                 // sX[cur] fully written
    float4 f0 = *(const float4*)&sX[cur][p0][rl * 4];
    float4 f1 = *(const float4*)&sX[cur][p1][rl * 4];
    float xs[8] = {f0.x, f0.y, f0.z, f0.w, f1.x, f1.y, f1.z, f1.w};
    short8 ah, al;
#pragma unroll
    for (int j = 0; j < 8; ++j) {
      unsigned short h = f2bf_rn(xs[j]);
      ah[j] = (short)h;
      al[j] = (short)f2bf_rn(xs[j] - bf2f(h));
    }
    acc_hh = __builtin_amdgcn_mfma_f32_16x16x32_bf16(ah, wh[c], acc_hh, 0, 0, 0);
    acc_hl = __builtin_amdgcn_mfma_f32_16x16x32_bf16(ah, wl[c], acc_hl, 0, 0, 0);
    acc_lh = __builtin_amdgcn_mfma_f32_16x16x32_bf16(al, wh[c], acc_lh, 0, 0, 0);
    __syncthreads();                 // all reads of sX[cur^1]'s target done
    if (c < 15) {
      int nb = (c + 1) & 1;
      *(float4*)&sX[nb][o0s][r0s * 4] = va;
      *(float4*)&sX[nb][o1s][r1s * 4] = vb;
    }
  }

  float a1c = a1[col], a2c = a2[col];
  int rowbase = row0 + w * 16;
#pragma unroll
  for (int r = 0; r < 4; ++r) {
    float v = acc_hh[r] + acc_hl[r] + acc_lh[r];
    int row = rowbase + quad * 4 + r;
    float p1e = v * a1c, p2e = v * a2c;
#pragma unroll
    for (int d = 1; d < 16; d <<= 1) { p1e += __shfl_xor(p1e, d); p2e += __shfl_xor(p2e, d); }
    if (row < N_NODES) {
      Hout[(size_t)row * 16 + col] = v;
      if (col == 0) phv[row] = make_float2(p1e, p2e);
    }
  }
}

// ---------------- K1: gemm1 || hist || eoff ----------------
__global__ __launch_bounds__(256) void k1_kernel(
    const float* __restrict__ X, const float* __restrict__ W1,
    const float* __restrict__ a1_1, const float* __restrict__ a2_1,
    float* __restrict__ Hout, float2* __restrict__ phv,
    const int* __restrict__ eidx, int* __restrict__ eoff,
    const int* __restrict__ nidx, int* __restrict__ gcnt) {
  int b = blockIdx.x;
  if (b < G_GEMM) {
    gemm1_body(b, X, W1, a1_1, a2_1, Hout, phv);
  } else if (b < G_GEMM + G_HIST) {
    hist_body(b - G_GEMM, nidx, gcnt);
  } else {
    eoff_body(b - G_GEMM - G_HIST, eidx, eoff);
  }
}

// ---------------- edge phase 1 (D=16, GROUP=16): 4-wide online softmax ----------
__device__ __forceinline__ void edge1_body(
    const float* __restrict__ h, const float2* __restrict__ phv,
    const float* __restrict__ a2, const int* __restrict__ eoff,
    const int* __restrict__ nidx, float* __restrict__ eout,
    float* __restrict__ pe, int wave, int lane) {
  if (wave >= N_EDGESC) return;
  int o0 = eoff[wave], o1 = eoff[wave + 1];
  int g = lane >> 4, t = lane & 15;
  if (o0 == o1) {
    if (g == 0) {
      eout[(size_t)wave * 16 + t] = 0.f;
      if (t == 0) pe[wave] = 0.f;
    }
    return;
  }
  float m = -1e30f, l = 0.f, acc = 0.f;
  for (int base = o0; base < o1; base += 64) {
    int nrem = o1 - base; if (nrem > 64) nrem = 64;
    int li = base + lane;
    int idx_l = nidx[li < o1 ? li : o1 - 1];
    for (int jb = 0; jb < nrem; jb += 16) {   // uniform bound; g in [0,4)
      int j = jb + g;                          // j+12 <= 63
      bool ok0 = j < nrem, ok1 = j + 4 < nrem, ok2 = j + 8 < nrem, ok3 = j + 12 < nrem;
      int v0 = __shfl(idx_l, j);
      int v1 = __shfl(idx_l, j + 4);
      int v2 = __shfl(idx_l, j + 8);
      int v3 = __shfl(idx_l, j + 12);
      float P0 = phv[v0].x, P1 = phv[v1].x, P2 = phv[v2].x, P3 = phv[v3].x;
      float h0 = h[(size_t)v0 * 16 + t];
      float h1 = h[(size_t)v1 * 16 + t];
      float h2 = h[(size_t)v2 * 16 + t];
      float h3 = h[(size_t)v3 * 16 + t];
      float s0 = ok0 ? (P0 > 0.f ? P0 : 0.2f * P0) : -1e30f;
      float s1 = ok1 ? (P1 > 0.f ? P1 : 0.2f * P1) : -1e30f;
      float s2 = ok2 ? (P2 > 0.f ? P2 : 0.2f * P2) : -1e30f;
      float s3 = ok3 ? (P3 > 0.f ? P3 : 0.2f * P3) : -1e30f;
      float mn = fmaxf(fmaxf(m, fmaxf(s0, s1)), fmaxf(s2, s3));
      float eo = __expf(m - mn);
      float e0 = ok0 ? __expf(s0 - mn) : 0.f;
      float e1 = ok1 ? __expf(s1 - mn) : 0.f;
      float e2 = ok2 ? __expf(s2 - mn) : 0.f;
      float e3 = ok3 ? __expf(s3 - mn) : 0.f;
      l = l * eo + ((e0 + e1) + (e2 + e3));
      acc = acc * eo + ((e0 * h0 + e1 * h1) + (e2 * h2 + e3 * h3));
      m = mn;
    }
  }
#pragma unroll
  for (int d = 16; d < 64; d <<= 1) {
    float mo = __shfl_xor(m, d), lo = __shfl_xor(l, d), ao = __shfl_xor(acc, d);
    float mn = fmaxf(m, mo);
    float ea = __expf(m - mn), eb = __expf(mo - mn);
    l = l * ea + lo * eb;
    acc = acc * ea + ao * eb;
    m = mn;
  }
  float val = acc / (l + 1e-9f);
  float pav = val * a2[16 + t];
#pragma unroll
  for (int d = 1; d < 16; d <<= 1) pav += __shfl_xor(pav, d);
  if (g == 0) {
    eout[(size_t)wave * 16 + t] = val;
    if (t == 0) pe[wave] = pav;
  }
}

// ---------------- K3: bin || edge1 ----------------
__global__ __launch_bounds__(256) void k3_kernel(
    const int* __restrict__ nidx, const int* __restrict__ eidx,
    int* __restrict__ bcur, int* __restrict__ binned,
    const float* __restrict__ h1g, const float2* __restrict__ phv,
    const float* __restrict__ a2_1, const int* __restrict__ eoff,
    float* __restrict__ e1, float* __restrict__ pe) {
  int b = blockIdx.x;
  if (b < G_BIN) {
    bin_body(b, nidx, eidx, bcur, binned);
  } else {
    int wave = (b - G_BIN) * 4 + (threadIdx.x >> 6);
    edge1_body(h1g, phv, a2_1, eoff, nidx, e1, pe, wave, threadIdx.x & 63);
  }
}

// ---------------- node phase 1 (D=16), 4-wide + fused gemm2 (packed h2g8) --------
__global__ __launch_bounds__(256) void node1_kernel(
    const float2* __restrict__ phv, const float* __restrict__ e1,
    const float* __restrict__ pe, const int* __restrict__ noff,
    const int* __restrict__ perm_e, float* __restrict__ H1out,
    float* __restrict__ h2g8, const float* __restrict__ W2,
    const float* __restrict__ a1_2, const float* __restrict__ a2_2,
    float* __restrict__ pn2) {
  int wave = (blockIdx.x * blockDim.x + threadIdx.x) >> 6;
  int lane = threadIdx.x & 63;
  if (wave >= N_NODES) return;
  int o0 = noff[wave], o1 = noff[wave + 1];
  int g = lane >> 4, t = lane & 15;
  float ph = phv[wave].y;
  float m = -1e30f, l = 0.f, acc = 0.f;
  for (int base = o0; base < o1; base += 64) {
    int nrem = o1 - base; if (nrem > 64) nrem = 64;
    int li = base + lane;
    int idx_l = perm_e[li < o1 ? li : o1 - 1];
    for (int jb = 0; jb < nrem; jb += 16) {   // uniform bound; g in [0,4)
      int j = jb + g;                          // j+12 <= 63
      bool ok0 = j < nrem, ok1 = j + 4 < nrem, ok2 = j + 8 < nrem, ok3 = j + 12 < nrem;
      int E0 = __shfl(idx_l, j);
      int E1 = __shfl(idx_l, j + 4);
      int E2 = __shfl(idx_l, j + 8);
      int E3 = __shfl(idx_l, j + 12);
      float P0 = ph + pe[E0], P1 = ph + pe[E1], P2 = ph + pe[E2], P3 = ph + pe[E3];
      float h0 = e1[(size_t)E0 * 16 + t];
      float h1 = e1[(size_t)E1 * 16 + t];
      float h2 = e1[(size_t)E2 * 16 + t];
      float h3 = e1[(size_t)E3 * 16 + t];
      float s0 = ok0 ? (P0 > 0.f ? P0 : 0.2f * P0) : -1e30f;
      float s1 = ok1 ? (P1 > 0.f ? P1 : 0.2f * P1) : -1e30f;
      float s2 = ok2 ? (P2 > 0.f ? P2 : 0.2f * P2) : -1e30f;
      float s3 = ok3 ? (P3 > 0.f ? P3 : 0.2f * P3) : -1e30f;
      float mn = fmaxf(fmaxf(m, fmaxf(s0, s1)), fmaxf(s2, s3));
      float eo = __expf(m - mn);
      float e0 = ok0 ? __expf(s0 - mn) : 0.f;
      float e1x = ok1 ? __expf(s1 - mn) : 0.f;
      float e2x = ok2 ? __expf(s2 - mn) : 0.f;
      float e3x = ok3 ? __expf(s3 - mn) : 0.f;
      l = l * eo + ((e0 + e1x) + (e2x + e3x));
      acc = acc * eo + ((e0 * h0 + e1x * h1) + (e2x * h2 + e3x * h3));
      m = mn;
    }
  }
#pragma unroll
  for (int d = 16; d < 64; d <<= 1) {
    float mo = __shfl_xor(m, d), lo = __shfl_xor(l, d), ao = __shfl_xor(acc, d);
    float ea_, eb_;
    float mn = fmaxf(m, mo);
    ea_ = __expf(m - mn); eb_ = __expf(mo - mn);
    l = l * ea_ + lo * eb_;
    acc = acc * ea_ + ao * eb_;
    m = mn;
  }
  float val = acc / (l + 1e-9f);            // H1[wave][t] (empty -> 0, matches ref)
  if (g == 0) H1out[(size_t)wave * 16 + t] = val;
  // fused gemm2: h2 = elu(H1) @ W2; pack row8 = [h2[0..6], p1]; pn2 = h2 . a2_2
  float x = val > 0.f ? val : expm1f(val);
  float p1 = 0.f, p2s = 0.f, myh2 = 0.f;
#pragma unroll
  for (int j = 0; j < N_CLS; ++j) {
    float term = x * W2[t * N_CLS + j];
#pragma unroll
    for (int d = 1; d < 16; d <<= 1) term += __shfl_xor(term, d);
    p1 += term * a1_2[j];
    p2s += term * a2_2[j];
    if (t == j) myh2 = term;
  }
  if (g == 0) {
    if (t < N_CLS) h2g8[(size_t)wave * 8 + t] = myh2;
    if (t == 7) h2g8[(size_t)wave * 8 + 7] = p1;
    if (t == 0) pn2[wave] = p2s;
  }
}

// ---------------- edge phase 2 (GROUP=8, packed rows [7 vals, score]) ----------------
__global__ __launch_bounds__(256) void edge2_kernel(
    const float* __restrict__ h2g8, const int* __restrict__ eoff,
    const int* __restrict__ nidx, const float* __restrict__ a2_2,
    float* __restrict__ e28) {
  int wave = (blockIdx.x * blockDim.x + threadIdx.x) >> 6;
  int lane = threadIdx.x & 63;
  if (wave >= N_EDGESC) return;
  int o0 = eoff[wave], o1 = eoff[wave + 1];
  int g = lane >> 3, t = lane & 7;
  if (o0 == o1) {
    if (g == 0) e28[(size_t)wave * 8 + t] = 0.f;   // vals + pe all zero
    return;
  }
  float m = -1e30f, l = 0.f, acc = 0.f;
  for (int base = o0; base < o1; base += 64) {
    int nrem = o1 - base; if (nrem > 64) nrem = 64;
    int li = base + lane;
    int idx_l = nidx[li < o1 ? li : o1 - 1];
    for (int jb = 0; jb < nrem; jb += 32) {   // uniform bound; g in [0,8)
      int j = jb + g;                          // j+24 <= 63
      bool ok0 = j < nrem, ok1 = j + 8 < nrem, ok2 = j + 16 < nrem, ok3 = j + 24 < nrem;
      int v0 = __shfl(idx_l, j);
      int v1 = __shfl(idx_l, j + 8);
      int v2 = __shfl(idx_l, j + 16);
      int v3 = __shfl(idx_l, j + 24);
      float f0 = h2g8[(size_t)v0 * 8 + t];
      float f1 = h2g8[(size_t)v1 * 8 + t];
      float f2 = h2g8[(size_t)v2 * 8 + t];
      float f3 = h2g8[(size_t)v3 * 8 + t];
      // slot 7 carries p1 = h2 . a1_2 ; broadcast within the 8-lane group
      float P0 = __shfl(f0, lane | 7);
      float P1 = __shfl(f1, lane | 7);
      float P2 = __shfl(f2, lane | 7);
      float P3 = __shfl(f3, lane | 7);
      float h0 = (t < 7) ? f0 : 0.f;
      float h1 = (t < 7) ? f1 : 0.f;
      float h2v = (t < 7) ? f2 : 0.f;
      float h3 = (t < 7) ? f3 : 0.f;
      float s0 = ok0 ? (P0 > 0.f ? P0 : 0.2f * P0) : -1e30f;
      float s1 = ok1 ? (P1 > 0.f ? P1 : 0.2f * P1) : -1e30f;
      float s2 = ok2 ? (P2 > 0.f ? P2 : 0.2f * P2) : -1e30f;
      float s3 = ok3 ? (P3 > 0.f ? P3 : 0.2f * P3) : -1e30f;
      float mn = fmaxf(fmaxf(m, fmaxf(s0, s1)), fmaxf(s2, s3));
      float eo = __expf(m - mn);
      float e0 = ok0 ? __expf(s0 - mn) : 0.f;
      float e1 = ok1 ? __expf(s1 - mn) : 0.f;
      float e2 = ok2 ? __expf(s2 - mn) : 0.f;
      float e3 = ok3 ? __expf(s3 - mn) : 0.f;
      l = l * eo + ((e0 + e1) + (e2 + e3));
      acc = acc * eo + ((e0 * h0 + e1 * h1) + (e2 * h2v + e3 * h3));
      m = mn;
    }
  }
#pragma unroll
  for (int d = 8; d < 64; d <<= 1) {
    float mo = __shfl_xor(m, d), lo = __shfl_xor(l, d), ao = __shfl_xor(acc, d);
    float mn = fmaxf(m, mo);
    float ea = __expf(m - mn), eb = __expf(mo - mn);
    l = l * ea + lo * eb;
    acc = acc * ea + ao * eb;
    m = mn;
  }
  float val = acc / (l + 1e-9f);
  float pav = (t < 7) ? val * a2_2[7 + t] : 0.f;
#pragma unroll
  for (int d = 1; d < 8; d <<= 1) pav += __shfl_xor(pav, d);
  if (g == 0) e28[(size_t)wave * 8 + t] = (t < 7) ? val : pav;   // slot 7 = pe
}

// ---------------- node phase 2 (GROUP=8, packed rows) + fused log_softmax ----------
__global__ __launch_bounds__(256) void node2_kernel(
    const float* __restrict__ e28, const float* __restrict__ pn2,
    const int* __restrict__ noff, const int* __restrict__ perm_e,
    float* __restrict__ H2out, float* __restrict__ logp) {
  int wave = (blockIdx.x * blockDim.x + threadIdx.x) >> 6;
  int lane = threadIdx.x & 63;
  if (wave >= N_NODES) return;
  int o0 = noff[wave], o1 = noff[wave + 1];
  int g = lane >> 3, t = lane & 7;
  float ph = pn2[wave];
  float m = -1e30f, l = 0.f, acc = 0.f;
  for (int base = o0; base < o1; base += 64) {
    int nrem = o1 - base; if (nrem > 64) nrem = 64;
    int li = base + lane;
    int idx_l = perm_e[li < o1 ? li : o1 - 1];
    for (int jb = 0; jb < nrem; jb += 32) {   // uniform bound; g in [0,8)
      int j = jb + g;                          // j+24 <= 63
      bool ok0 = j < nrem, ok1 = j + 8 < nrem, ok2 = j + 16 < nrem, ok3 = j + 24 < nrem;
      int E0 = __shfl(idx_l, j);
      int E1 = __shfl(idx_l, j + 8);
      int E2 = __shfl(idx_l, j + 16);
      int E3 = __shfl(idx_l, j + 24);
      float f0 = e28[(size_t)E0 * 8 + t];
      float f1 = e28[(size_t)E1 * 8 + t];
      float f2 = e28[(size_t)E2 * 8 + t];
      float f3 = e28[(size_t)E3 * 8 + t];
      // slot 7 carries pe; broadcast within group
      float P0 = ph + __shfl(f0, lane | 7);
      float P1 = ph + __shfl(f1, lane | 7);
      float P2 = ph + __shfl(f2, lane | 7);
      float P3 = ph + __shfl(f3, lane | 7);
      float h0 = (t < 7) ? f0 : 0.f;
      float h1 = (t < 7) ? f1 : 0.f;
      float h2v = (t < 7) ? f2 : 0.f;
      float h3 = (t < 7) ? f3 : 0.f;
      float s0 = ok0 ? (P0 > 0.f ? P0 : 0.2f * P0) : -1e30f;
      float s1 = ok1 ? (P1 > 0.f ? P1 : 0.2f * P1) : -1e30f;
      float s2 = ok2 ? (P2 > 0.f ? P2 : 0.2f * P2) : -1e30f;
      float s3 = ok3 ? (P3 > 0.f ? P3 : 0.2f * P3) : -1e30f;
      float mn = fmaxf(fmaxf(m, fmaxf(s0, s1)), fmaxf(s2, s3));
      float eo = __expf(m - mn);
      float e0 = ok0 ? __expf(s0 - mn) : 0.f;
      float e1 = ok1 ? __expf(s1 - mn) : 0.f;
      float e2 = ok2 ? __expf(s2 - mn) : 0.f;
      float e3 = ok3 ? __expf(s3 - mn) : 0.f;
      l = l * eo + ((e0 + e1) + (e2 + e3));
      acc = acc * eo + ((e0 * h0 + e1 * h1) + (e2 * h2v + e3 * h3));
      m = mn;
    }
  }
#pragma unroll
  for (int d = 8; d < 64; d <<= 1) {
    float mo = __shfl_xor(m, d), lo = __shfl_xor(l, d), ao = __shfl_xor(acc, d);
    float mn = fmaxf(m, mo);
    float ea = __expf(m - mn), eb = __expf(mo - mn);
    l = l * ea + lo * eb;
    acc = acc * ea + ao * eb;
    m = mn;
  }
  float val = acc / (l + 1e-9f);            // H2[wave][t] (empty -> 0)
  if (g == 0 && t < 7) H2out[(size_t)wave * 7 + t] = val;
  // fused log_softmax over 7 classes within each 8-lane group
  float xm = (t < 7) ? val : -1e30f;
#pragma unroll
  for (int d = 1; d < 8; d <<= 1) xm = fmaxf(xm, __shfl_xor(xm, d));
  float se = (t < 7) ? __expf(val - xm) : 0.f;
#pragma unroll
  for (int d = 1; d < 8; d <<= 1) se += __shfl_xor(se, d);
  float lg = logf(se);
  if (g == 0 && t < 7) logp[(size_t)wave * 7 + t] = val - xm - lg;
}

// ---------------- launch ----------------
extern "C" void kernel_launch(void* const* d_in, const int* in_sizes, int n_in,
                              void* d_out, int out_size, void* d_ws, size_t ws_size,
                              hipStream_t stream) {
  const float* H    = (const float*)d_in[0];
  const float* W1   = (const float*)d_in[1];
  const float* a1_1 = (const float*)d_in[2];
  const float* a2_1 = (const float*)d_in[3];
  const float* W2   = (const float*)d_in[4];
  const float* a1_2 = (const float*)d_in[5];
  const float* a2_2 = (const float*)d_in[6];
  const int* nidx   = (const int*)d_in[7];
  const int* eidx   = (const int*)d_in[8];

  float* outp = (float*)d_out;
  float* logp = outp;                                   // [N,7]
  float* H1   = outp + (size_t)N_NODES * N_CLS;         // [N,16]
  float* H2   = H1 + (size_t)N_NODES * D_HID;           // [N,7]

  char* ws = (char*)d_ws;
  float* h1g  = (float*)(ws + 0);          //  6,400,000 B : N x 16
  float* e1   = (float*)(ws + 6400000);    //  6,400,000 B : E x 16
  float* h2g8 = (float*)(ws + 12800000);   //  3,200,000 B : N x 8 [h2|p1]
  float* e28  = (float*)(ws + 16000000);   //  3,200,000 B : E x 8 [e2|pe]
  int* eoff   = (int*)(ws + 19200000);     //    400,004 B : E+1
  int* noff   = (int*)(ws + 19600128);     //    400,004 B : N+1
  float* pe   = (float*)(ws + 20000256);   //    400,000 B : E
  float* pn2  = (float*)(ws + 20400256);   //    400,000 B : N (h2 . a2_2)
  float2* phv = (float2*)(ws + 20800256);  //    800,000 B : N x {p_a1, p_a2}
  int* perm_e = (int*)(ws + 21600256);     // 12,800,000 B : NNZ
  int* gcnt   = (int*)(ws + 34400256);     //      3,128 B : NBK
  int* boff   = (int*)(ws + 34403456);     //      3,132 B : NBK+1
  int* bcur   = (int*)(ws + 34406656);     //      3,128 B : NBK
  int* binned = (int*)(ws + 34409856);     // 12,800,000 B : NNZ

  const int TB = 256;

  hipMemsetAsync(gcnt, 0, NBK * sizeof(int), stream);
  // K1: gemm1 (LDS-staged, BW-efficient) || hist || eoff
  k1_kernel<<<G_GEMM + G_HIST + G_EOFF, TB, 0, stream>>>(
      H, W1, a1_1, a2_1, h1g, phv, eidx, eoff, nidx, gcnt);
  bscan_kernel<<<1, 1024, 0, stream>>>(gcnt, boff, bcur);
  // K3: bin (fat blocks, coalesced scatter runs) || edge phase 1
  k3_kernel<<<G_BIN + 25000, TB, 0, stream>>>(
      nidx, eidx, bcur, binned, h1g, phv, a2_1, eoff, e1, pe);
  csr_kernel<<<NBK, TB, 0, stream>>>(binned, boff, noff, perm_e, N_NODES);
  // node phase 1 + fused gemm2 (packed h2g8) + pn2
  node1_kernel<<<25000, TB, 0, stream>>>(phv, e1, pe, noff, perm_e, H1, h2g8,
                                         W2, a1_2, a2_2, pn2);
  // layer 2 (packed rows)
  edge2_kernel<<<25000, TB, 0, stream>>>(h2g8, eoff, nidx, a2_2, e28);
  node2_kernel<<<25000, TB, 0, stream>>>(e28, pn2, noff, perm_e, H2, logp);
}